// Round 2
// baseline (584.905 us; speedup 1.0000x reference)
//
#include <hip/hip_runtime.h>
#include <math.h>

// ---------------- build Wcat (1024 x 512) fp32: rows = [q(256) | k(256) | v(512)] ----------------
__global__ __launch_bounds__(256) void build_wcat(const float* __restrict__ qp, const float* __restrict__ kp,
                                                  const float* __restrict__ wv, float* __restrict__ wcat) {
  int i = blockIdx.x * 256 + threadIdx.x;  // 0..524287
  int d = i & 511, c = i >> 9;
  float v;
  if (c < 512) {
    int hh = c >> 5, o = c & 31;
    const float* src = (hh < 8) ? qp : kp;
    int h = hh & 7;
    v = src[(h * 512 + d) * 32 + o];
  } else {
    v = wv[(c - 512) * 512 + d];
  }
  wcat[i] = v;
}

// ---------------- generic tiled GEMM: C[M x N] = A[M x 512] @ B^T (B: N x 512), all fp32 ----------------
// EPI: 0 = plain, 1 = + X, 2 = X + silu(acc).  X is fp32, N must be 512 for EPI 1/2.
template <int EPI>
__global__ __launch_bounds__(256) void gemm_bt(const float* __restrict__ A, const float* __restrict__ Bm,
                                               const float* __restrict__ X, float* __restrict__ C, int N) {
  __shared__ float As[16][64];
  __shared__ float Bs[16][64];
  const int tid = threadIdx.x;
  const int bm = blockIdx.y, bn = blockIdx.x;
  const int tr = tid >> 4, tc = tid & 15;
  const int lr = tid >> 2;          // 0..63
  const int lk = (tid & 3) << 2;    // 0,4,8,12
  float acc[4][4] = {};
  const float* Ap = A + (size_t)(bm * 64 + lr) * 512 + lk;
  const float* Bp = Bm + (size_t)(bn * 64 + lr) * 512 + lk;
  for (int k0 = 0; k0 < 512; k0 += 16) {
    float4 av = *(const float4*)(Ap + k0);
    float4 bv = *(const float4*)(Bp + k0);
    As[lk + 0][lr] = av.x; As[lk + 1][lr] = av.y; As[lk + 2][lr] = av.z; As[lk + 3][lr] = av.w;
    Bs[lk + 0][lr] = bv.x; Bs[lk + 1][lr] = bv.y; Bs[lk + 2][lr] = bv.z; Bs[lk + 3][lr] = bv.w;
    __syncthreads();
#pragma unroll
    for (int kk = 0; kk < 16; ++kk) {
      float4 a4 = *(const float4*)&As[kk][tr << 2];
      float4 b4 = *(const float4*)&Bs[kk][tc << 2];
      float aa[4] = {a4.x, a4.y, a4.z, a4.w};
      float bb[4] = {b4.x, b4.y, b4.z, b4.w};
#pragma unroll
      for (int i = 0; i < 4; i++)
#pragma unroll
        for (int j = 0; j < 4; j++) acc[i][j] = fmaf(aa[i], bb[j], acc[i][j]);
    }
    __syncthreads();
  }
  int m0 = bm * 64 + (tr << 2), n0 = bn * 64 + (tc << 2);
#pragma unroll
  for (int i = 0; i < 4; i++) {
    float r[4] = {acc[i][0], acc[i][1], acc[i][2], acc[i][3]};
    if (EPI == 1) {
      float4 xv = *(const float4*)&X[(size_t)(m0 + i) * 512 + n0];
      r[0] += xv.x; r[1] += xv.y; r[2] += xv.z; r[3] += xv.w;
    } else if (EPI == 2) {
      float4 xv = *(const float4*)&X[(size_t)(m0 + i) * 512 + n0];
      float xa[4] = {xv.x, xv.y, xv.z, xv.w};
#pragma unroll
      for (int j = 0; j < 4; j++) r[j] = xa[j] + r[j] / (1.f + __expf(-r[j]));
    }
    *(float4*)&C[(size_t)(m0 + i) * N + n0] = make_float4(r[0], r[1], r[2], r[3]);
  }
}

// ---------------- RoPE + gain + score-scale fold; scatter q,k -> (b,h,t,32) ----------------
__global__ __launch_bounds__(256) void rope_kernel(const float* __restrict__ qkv, const float* __restrict__ qgain,
                                                   float* __restrict__ qr, float* __restrict__ kr) {
  int gid = blockIdx.x * 256 + threadIdx.x;  // B*H*T*16 = 524288
  int o = gid & 15;
  int t = (gid >> 4) & 2047;
  int h = (gid >> 15) & 7;
  int b = gid >> 18;
  const float* row = qkv + (size_t)(b * 2048 + t) * 1024;
  float freq = powf(10000.f, -(float)o / 16.f);
  float ang = (float)t * freq;
  float s, c;
  sincosf(ang, &s, &c);
  float g = qgain[h] * 0.17677669529663687f;  // gain * 1/sqrt(32)
  int qb = h * 32;
  float q0 = row[qb + o], q1 = row[qb + o + 16];
  float k0 = row[256 + qb + o], k1 = row[256 + qb + o + 16];
  float* qo = qr + ((size_t)((b * 8 + h) * 2048 + t)) * 32;
  float* ko = kr + ((size_t)((b * 8 + h) * 2048 + t)) * 32;
  qo[o] = (q0 * c - q1 * s) * g;
  qo[o + 16] = (q1 * c + q0 * s) * g;
  ko[o] = k0 * c - k1 * s;
  ko[o + 16] = k1 * c + k0 * s;
}

// ---------------- causal flash attention: block = (b,h,qtile of 64) ----------------
__global__ __launch_bounds__(256) void attn_kernel(const float* __restrict__ qarr, const float* __restrict__ karr,
                                                   const float* __restrict__ qkv, float* __restrict__ y) {
  const int qt = blockIdx.x & 31, h = (blockIdx.x >> 5) & 7, b = blockIdx.x >> 8;
  const int tid = threadIdx.x, tr = tid >> 4, tc = tid & 15;
  __shared__ float Qt_s[32][64];  // [o][r]
  __shared__ float Kt_s[32][64];  // [o][c]
  __shared__ float Vs[64][64];    // [c][dv]
  __shared__ float Ps[64][68];    // [r][c] padded

  float acc[4][4] = {};
  float m_i[4], l_i[4];
#pragma unroll
  for (int i = 0; i < 4; i++) { m_i[i] = -INFINITY; l_i[i] = 0.f; }

  // load Q tile, transposed into LDS
  {
    const float* qbase = qarr + ((size_t)((b * 8 + h) * 2048 + qt * 64)) * 32;
#pragma unroll
    for (int it = 0; it < 2; ++it) {
      int f4 = tid + it * 256;
      int r = f4 >> 3, o4 = (f4 & 7) * 4;
      float4 v = *(const float4*)(qbase + r * 32 + o4);
      Qt_s[o4 + 0][r] = v.x; Qt_s[o4 + 1][r] = v.y; Qt_s[o4 + 2][r] = v.z; Qt_s[o4 + 3][r] = v.w;
    }
  }
  const float* vbase = qkv + (size_t)(b * 2048) * 1024 + 512 + h * 64;
  const float* kbh = karr + ((size_t)((b * 8 + h) * 2048)) * 32;

  for (int kt = 0; kt <= qt; ++kt) {
    __syncthreads();  // protects Kt/Vs/Ps reuse; also fences initial Q load
    const float* kbase = kbh + (size_t)(kt * 64) * 32;
#pragma unroll
    for (int it = 0; it < 2; ++it) {
      int f4 = tid + it * 256;
      int r = f4 >> 3, o4 = (f4 & 7) * 4;
      float4 v = *(const float4*)(kbase + r * 32 + o4);
      Kt_s[o4 + 0][r] = v.x; Kt_s[o4 + 1][r] = v.y; Kt_s[o4 + 2][r] = v.z; Kt_s[o4 + 3][r] = v.w;
    }
#pragma unroll
    for (int it = 0; it < 4; ++it) {
      int f4 = tid + it * 256;  // 1024 float4s
      int r = f4 >> 4, c4 = (f4 & 15) * 4;
      *(float4*)&Vs[r][c4] = *(const float4*)(vbase + (size_t)(kt * 64 + r) * 1024 + c4);
    }
    __syncthreads();

    // S = Q K^T (per-thread 4x4)
    float s[4][4] = {};
#pragma unroll
    for (int o = 0; o < 32; o++) {
      float4 qv = *(const float4*)&Qt_s[o][tr << 2];
      float4 kv = *(const float4*)&Kt_s[o][tc << 2];
      float qa[4] = {qv.x, qv.y, qv.z, qv.w};
      float ka[4] = {kv.x, kv.y, kv.z, kv.w};
#pragma unroll
      for (int i = 0; i < 4; i++)
#pragma unroll
        for (int j = 0; j < 4; j++) s[i][j] = fmaf(qa[i], ka[j], s[i][j]);
    }
    if (kt == qt) {
#pragma unroll
      for (int i = 0; i < 4; i++)
#pragma unroll
        for (int j = 0; j < 4; j++)
          if ((tc << 2) + j > (tr << 2) + i) s[i][j] = -1e30f;
    }

    // online softmax update (rows owned by 16 contiguous lanes)
#pragma unroll
    for (int i = 0; i < 4; i++) {
      float pm = fmaxf(fmaxf(s[i][0], s[i][1]), fmaxf(s[i][2], s[i][3]));
#pragma unroll
      for (int mk = 1; mk < 16; mk <<= 1) pm = fmaxf(pm, __shfl_xor(pm, mk, 64));
      float mnew = fmaxf(m_i[i], pm);
      float alpha = __expf(m_i[i] - mnew);
      m_i[i] = mnew;
      l_i[i] *= alpha;
#pragma unroll
      for (int j = 0; j < 4; j++) acc[i][j] *= alpha;
      float p0 = __expf(s[i][0] - mnew), p1 = __expf(s[i][1] - mnew);
      float p2 = __expf(s[i][2] - mnew), p3 = __expf(s[i][3] - mnew);
      float psum = p0 + p1 + p2 + p3;
#pragma unroll
      for (int mk = 1; mk < 16; mk <<= 1) psum += __shfl_xor(psum, mk, 64);
      l_i[i] += psum;
      *(float4*)&Ps[(tr << 2) + i][tc << 2] = make_float4(p0, p1, p2, p3);
    }
    __syncthreads();

    // acc += P @ V
#pragma unroll 4
    for (int c4 = 0; c4 < 16; c4++) {
      float p[4][4];
#pragma unroll
      for (int i = 0; i < 4; i++) {
        float4 pv = *(const float4*)&Ps[(tr << 2) + i][c4 << 2];
        p[i][0] = pv.x; p[i][1] = pv.y; p[i][2] = pv.z; p[i][3] = pv.w;
      }
#pragma unroll
      for (int cc = 0; cc < 4; cc++) {
        float4 vv = *(const float4*)&Vs[(c4 << 2) + cc][tc << 2];
        float va[4] = {vv.x, vv.y, vv.z, vv.w};
#pragma unroll
        for (int i = 0; i < 4; i++)
#pragma unroll
          for (int j = 0; j < 4; j++) acc[i][j] = fmaf(p[i][cc], va[j], acc[i][j]);
      }
    }
  }

  float* yb = y + ((size_t)((b * 8 + h) * 2048 + qt * 64)) * 64;
#pragma unroll
  for (int i = 0; i < 4; i++) {
    float inv = 1.f / l_i[i];
    *(float4*)&yb[((tr << 2) + i) * 64 + (tc << 2)] =
        make_float4(acc[i][0] * inv, acc[i][1] * inv, acc[i][2] * inv, acc[i][3] * inv);
  }
}

// ---------------- self-align correction + permute to (b,t,512); one wave per row ----------------
__global__ __launch_bounds__(256) void align_correct(const float* __restrict__ y, const float* __restrict__ qkv,
                                                     float* __restrict__ y2) {
  int ridx = blockIdx.x * 4 + (threadIdx.x >> 6);
  int lane = threadIdx.x & 63;
  int t = ridx & 2047, h = (ridx >> 11) & 7, b = ridx >> 14;
  float yv = y[(size_t)ridx * 64 + lane];
  float vv = qkv[(size_t)(b * 2048 + t) * 1024 + 512 + h * 64 + lane];
  float ss = vv * vv;
#pragma unroll
  for (int mk = 1; mk < 64; mk <<= 1) ss += __shfl_xor(ss, mk, 64);
  float vn = vv / fmaxf(sqrtf(ss), 1e-12f);
  float d = yv * vn;
#pragma unroll
  for (int mk = 1; mk < 64; mk <<= 1) d += __shfl_xor(d, mk, 64);
  y2[(size_t)(b * 2048 + t) * 512 + h * 64 + lane] = yv - d * vn;
}

// ---------------- LayerNorm / RMSNorm: one wave per 512-row ----------------
template <bool RMS>
__global__ __launch_bounds__(256) void norm_kernel(const float* __restrict__ in, const float* __restrict__ g,
                                                   const float* __restrict__ bglob, float* __restrict__ out) {
  int row = blockIdx.x * 4 + (threadIdx.x >> 6);
  int lane = threadIdx.x & 63;
  const float* rp = in + (size_t)row * 512 + lane * 8;
  float4 a = *(const float4*)rp;
  float4 b = *(const float4*)(rp + 4);
  float v[8] = {a.x, a.y, a.z, a.w, b.x, b.y, b.z, b.w};
  float mean = 0.f, inv;
  if (!RMS) {
    float s = 0.f;
#pragma unroll
    for (int e = 0; e < 8; e++) s += v[e];
#pragma unroll
    for (int mk = 1; mk < 64; mk <<= 1) s += __shfl_xor(s, mk, 64);
    mean = s * (1.f / 512.f);
    float vs = 0.f;
#pragma unroll
    for (int e = 0; e < 8; e++) { float d = v[e] - mean; vs = fmaf(d, d, vs); }
#pragma unroll
    for (int mk = 1; mk < 64; mk <<= 1) vs += __shfl_xor(vs, mk, 64);
    inv = rsqrtf(vs * (1.f / 512.f) + 1e-5f);
  } else {
    float vs = 0.f;
#pragma unroll
    for (int e = 0; e < 8; e++) vs = fmaf(v[e], v[e], vs);
#pragma unroll
    for (int mk = 1; mk < 64; mk <<= 1) vs += __shfl_xor(vs, mk, 64);
    inv = rsqrtf(vs * (1.f / 512.f) + 1e-6f);
  }
  float o[8];
  if (!RMS) {
    int c0 = lane * 8;
#pragma unroll
    for (int e = 0; e < 8; e++) o[e] = (v[e] - mean) * inv * g[c0 + e] + bglob[c0 + e];
  } else {
#pragma unroll
    for (int e = 0; e < 8; e++) o[e] = v[e] * inv;
  }
  float* op = out + (size_t)row * 512 + lane * 8;
  *(float4*)op = make_float4(o[0], o[1], o[2], o[3]);
  *(float4*)(op + 4) = make_float4(o[4], o[5], o[6], o[7]);
}

// ---------------- final 512->32 projection + softplus temp + tanh ----------------
__global__ __launch_bounds__(256) void final_kernel(const float* __restrict__ r, const float* __restrict__ wout,
                                                    const float* __restrict__ ct, float* __restrict__ z) {
  int tok = blockIdx.x * 8 + (threadIdx.x >> 5);
  int n = threadIdx.x & 31;
  const float* rr = r + (size_t)tok * 512;
  const float* w = wout + (size_t)n * 512;
  float acc = 0.f;
  for (int d = 0; d < 512; d += 4) {
    float4 rv = *(const float4*)(rr + d);
    float4 wv = *(const float4*)(w + d);
    acc = fmaf(rv.x, wv.x, acc);
    acc = fmaf(rv.y, wv.y, acc);
    acc = fmaf(rv.z, wv.z, acc);
    acc = fmaf(rv.w, wv.w, acc);
  }
  float c = ct[n];
  float sp = (c > 20.f) ? c : log1pf(__expf(c));
  z[(size_t)tok * 32 + n] = tanhf(acc / (sp + 1e-4f));
}

extern "C" void kernel_launch(void* const* d_in, const int* in_sizes, int n_in,
                              void* d_out, int out_size, void* d_ws, size_t ws_size,
                              hipStream_t stream) {
  const float* x = (const float*)d_in[0];
  const float* qp = (const float*)d_in[1];
  const float* kp = (const float*)d_in[2];
  const float* wv = (const float*)d_in[3];
  const float* wpr = (const float*)d_in[4];
  const float* qg = (const float*)d_in[5];
  const float* w0 = (const float*)d_in[6];
  const float* g1 = (const float*)d_in[7];
  const float* b1 = (const float*)d_in[8];
  const float* w1 = (const float*)d_in[9];
  const float* g2 = (const float*)d_in[10];
  const float* b2 = (const float*)d_in[11];
  const float* w2 = (const float*)d_in[12];
  const float* wout = (const float*)d_in[13];
  const float* ct = (const float*)d_in[14];
  float* z = (float*)d_out;

  float* ws = (float*)d_ws;
  const size_t MEG = 1024 * 1024;
  float* A_QKV = ws;                 // 4M floats: qkv raw; reused as he0
  float* A_Q = ws + 4 * MEG;         // 1M
  float* A_K = ws + 5 * MEG;         // 1M
  float* A_Y = ws + 6 * MEG;         // 2M: attn out; reused as he1
  float* A_Y2 = ws + 8 * MEG;        // 2M: permuted y; reused as he2
  float* A_H = ws + 10 * MEG;        // 2M: h; reused as rms out
  float* A_LN = ws + 12 * MEG;       // 2M: LN scratch
  float* WCAT = ws + 14 * MEG;       // 0.5M floats

  hipLaunchKernelGGL(build_wcat, dim3(2048), dim3(256), 0, stream, qp, kp, wv, WCAT);
  hipLaunchKernelGGL((gemm_bt<0>), dim3(16, 64), dim3(256), 0, stream, x, WCAT, (const float*)nullptr, A_QKV, 1024);
  hipLaunchKernelGGL(rope_kernel, dim3(2048), dim3(256), 0, stream, A_QKV, qg, A_Q, A_K);
  hipLaunchKernelGGL(attn_kernel, dim3(512), dim3(256), 0, stream, A_Q, A_K, A_QKV, A_Y);
  hipLaunchKernelGGL(align_correct, dim3(8192), dim3(256), 0, stream, A_Y, A_QKV, A_Y2);
  hipLaunchKernelGGL((gemm_bt<1>), dim3(8, 64), dim3(256), 0, stream, A_Y2, wpr, x, A_H, 512);
  hipLaunchKernelGGL((gemm_bt<0>), dim3(8, 64), dim3(256), 0, stream, A_H, w0, (const float*)nullptr, A_QKV, 512);
  hipLaunchKernelGGL((norm_kernel<false>), dim3(1024), dim3(256), 0, stream, A_QKV, g1, b1, A_LN);
  hipLaunchKernelGGL((gemm_bt<2>), dim3(8, 64), dim3(256), 0, stream, A_LN, w1, A_H, A_Y, 512);
  hipLaunchKernelGGL((norm_kernel<false>), dim3(1024), dim3(256), 0, stream, A_Y, g2, b2, A_LN);
  hipLaunchKernelGGL((gemm_bt<2>), dim3(8, 64), dim3(256), 0, stream, A_LN, w2, A_Y, A_Y2, 512);
  hipLaunchKernelGGL((norm_kernel<true>), dim3(1024), dim3(256), 0, stream, A_Y2, (const float*)nullptr, (const float*)nullptr, A_H);
  hipLaunchKernelGGL(final_kernel, dim3(512), dim3(256), 0, stream, A_H, wout, ct, z);
}

// Round 4
// 353.061 us; speedup vs baseline: 1.6567x; 1.6567x over previous
//
#include <hip/hip_runtime.h>
#include <math.h>

typedef unsigned short u16;
typedef __attribute__((ext_vector_type(8))) short short8;
typedef __attribute__((ext_vector_type(4))) float floatx4;

__device__ __forceinline__ float b2f(u16 u) { return __uint_as_float(((unsigned)u) << 16); }
__device__ __forceinline__ u16 f2b(float f) {
  unsigned u = __float_as_uint(f);
  return (u16)((u + 0x7fffu + ((u >> 16) & 1u)) >> 16);
}

// ---------------- cast fp32 -> bf16, 4 elems/thread (524288 float4s -> grid 2048) ----------------
__global__ __launch_bounds__(256) void cast_x(const float4* __restrict__ src, ushort4* __restrict__ dst) {
  int i = blockIdx.x * 256 + threadIdx.x;
  float4 v = src[i];
  ushort4 o; o.x = f2b(v.x); o.y = f2b(v.y); o.z = f2b(v.z); o.w = f2b(v.w);
  dst[i] = o;
}

// fused cast of the four 512x512 weights
__global__ __launch_bounds__(256) void cast_w4(const float* __restrict__ s0, const float* __restrict__ s1,
                                               const float* __restrict__ s2, const float* __restrict__ s3,
                                               u16* __restrict__ d0, u16* __restrict__ d1,
                                               u16* __restrict__ d2, u16* __restrict__ d3) {
  int i = blockIdx.x * 256 + threadIdx.x;  // 262144 float4s total
  int sel = i >> 16, j = i & 65535;
  const float* s = sel == 0 ? s0 : sel == 1 ? s1 : sel == 2 ? s2 : s3;
  u16* d = sel == 0 ? d0 : sel == 1 ? d1 : sel == 2 ? d2 : d3;
  float4 v = ((const float4*)s)[j];
  ushort4 o; o.x = f2b(v.x); o.y = f2b(v.y); o.z = f2b(v.z); o.w = f2b(v.w);
  ((ushort4*)d)[j] = o;
}

// ---------------- build Wcat (1024 x 512) bf16: rows = [q(256) | k(256) | v(512)] ----------------
__global__ __launch_bounds__(256) void build_wcat(const float* __restrict__ qp, const float* __restrict__ kp,
                                                  const float* __restrict__ wv, u16* __restrict__ wcat) {
  int i = blockIdx.x * 256 + threadIdx.x;  // 0..524287
  int d = i & 511, c = i >> 9;
  float v;
  if (c < 512) {
    int hh = c >> 5, o = c & 31;
    const float* src = (hh < 8) ? qp : kp;
    int h = hh & 7;
    v = src[(h * 512 + d) * 32 + o];
  } else {
    v = wv[(c - 512) * 512 + d];
  }
  wcat[i] = f2b(v);
}

// ---------------- bf16 MFMA GEMM: C[M x N] = A[M x 512] @ B^T (B: N x 512), bf16 in, fp32 acc ----
// EPI: 0 plain, 1 +X, 2 X + silu(acc). X fp32 stride 512. DUAL: also store bf16 copy.
template <int EPI, bool DUAL>
__global__ __launch_bounds__(256) void mgemm(const u16* __restrict__ A, const u16* __restrict__ Bw,
                                             const float* __restrict__ X, float* __restrict__ C,
                                             u16* __restrict__ Cb, int N) {
  __shared__ u16 As[64][40];  // +8 pad breaks bank alignment
  __shared__ u16 Bs[64][40];
  const int tid = threadIdx.x;
  const int bm = blockIdx.y, bn = blockIdx.x;
  const int lane = tid & 63, wave = tid >> 6;
  const int wm = wave >> 1, wn = wave & 1;
  const int quad = lane >> 4, l16 = lane & 15;
  const int sr = tid >> 2;        // staging row 0..63
  const int sk = (tid & 3) << 3;  // k-chunk 0,8,16,24
  floatx4 acc[2][2] = {};
  const u16* Ap = A + (size_t)(bm * 64 + sr) * 512 + sk;
  const u16* Bp = Bw + (size_t)(bn * 64 + sr) * 512 + sk;
  for (int k0 = 0; k0 < 512; k0 += 32) {
    uint4 av = *(const uint4*)(Ap + k0);
    uint4 bv = *(const uint4*)(Bp + k0);
    __syncthreads();
    *(uint4*)&As[sr][sk] = av;
    *(uint4*)&Bs[sr][sk] = bv;
    __syncthreads();
    short8 a0 = *(const short8*)&As[wm * 32 + l16][quad * 8];
    short8 a1 = *(const short8*)&As[wm * 32 + 16 + l16][quad * 8];
    short8 b0 = *(const short8*)&Bs[wn * 32 + l16][quad * 8];
    short8 b1 = *(const short8*)&Bs[wn * 32 + 16 + l16][quad * 8];
    acc[0][0] = __builtin_amdgcn_mfma_f32_16x16x32_bf16(a0, b0, acc[0][0], 0, 0, 0);
    acc[0][1] = __builtin_amdgcn_mfma_f32_16x16x32_bf16(a0, b1, acc[0][1], 0, 0, 0);
    acc[1][0] = __builtin_amdgcn_mfma_f32_16x16x32_bf16(a1, b0, acc[1][0], 0, 0, 0);
    acc[1][1] = __builtin_amdgcn_mfma_f32_16x16x32_bf16(a1, b1, acc[1][1], 0, 0, 0);
  }
#pragma unroll
  for (int mt = 0; mt < 2; mt++)
#pragma unroll
    for (int r = 0; r < 4; r++) {
      int row = bm * 64 + wm * 32 + mt * 16 + quad * 4 + r;
#pragma unroll
      for (int nt = 0; nt < 2; nt++) {
        int col = bn * 64 + wn * 32 + nt * 16 + l16;
        float v = acc[mt][nt][r];
        if (EPI == 1) {
          v += X[(size_t)row * 512 + col];
        } else if (EPI == 2) {
          float xv = X[(size_t)row * 512 + col];
          v = xv + v / (1.f + __expf(-v));
        }
        C[(size_t)row * N + col] = v;
        if (DUAL) Cb[(size_t)row * N + col] = f2b(v);
      }
    }
}

// ---------------- RoPE + gain + score-scale fold; scatter q,k -> (b,h,t,32) ----------------
__global__ __launch_bounds__(256) void rope_kernel(const float* __restrict__ qkv, const float* __restrict__ qgain,
                                                   float* __restrict__ qr, float* __restrict__ kr) {
  int gid = blockIdx.x * 256 + threadIdx.x;  // B*H*T*16 = 524288
  int o = gid & 15;
  int t = (gid >> 4) & 2047;
  int h = (gid >> 15) & 7;
  int b = gid >> 18;
  const float* row = qkv + (size_t)(b * 2048 + t) * 1024;
  float freq = powf(10000.f, -(float)o / 16.f);
  float ang = (float)t * freq;
  float s, c;
  sincosf(ang, &s, &c);
  float g = qgain[h] * 0.17677669529663687f;  // gain * 1/sqrt(32)
  int qb = h * 32;
  float q0 = row[qb + o], q1 = row[qb + o + 16];
  float k0 = row[256 + qb + o], k1 = row[256 + qb + o + 16];
  float* qo = qr + ((size_t)((b * 8 + h) * 2048 + t)) * 32;
  float* ko = kr + ((size_t)((b * 8 + h) * 2048 + t)) * 32;
  qo[o] = (q0 * c - q1 * s) * g;
  qo[o + 16] = (q1 * c + q0 * s) * g;
  ko[o] = k0 * c - k1 * s;
  ko[o + 16] = k1 * c + k0 * s;
}

// ---------------- causal flash attention: block = (b,h,qtile of 64), balanced remap ----------------
__global__ __launch_bounds__(256) void attn_kernel(const float* __restrict__ qarr, const float* __restrict__ karr,
                                                   const float* __restrict__ qkv, float* __restrict__ y) {
  // Blocks j and j+256 land on the same CU (round-robin); give them complementary
  // tiles q0 and 31-q0 so per-CU work is constant (33 k-iters).
  const int bi = blockIdx.x;
  const int gb = bi & 15;
  const int q0i = (bi >> 4) & 15;
  const int qt = (bi >> 8) ? (31 - q0i) : q0i;
  const int h = gb & 7, b = gb >> 3;
  const int tid = threadIdx.x, tr = tid >> 4, tc = tid & 15;
  __shared__ float Qt_s[32][64];  // [o][r]
  __shared__ float Kt_s[32][64];  // [o][c]
  __shared__ float Vs[64][64];    // [c][dv]
  __shared__ float Ps[64][68];    // [r][c] padded

  float acc[4][4] = {};
  float m_i[4], l_i[4];
#pragma unroll
  for (int i = 0; i < 4; i++) { m_i[i] = -INFINITY; l_i[i] = 0.f; }

  {
    const float* qbase = qarr + ((size_t)((b * 8 + h) * 2048 + qt * 64)) * 32;
#pragma unroll
    for (int it = 0; it < 2; ++it) {
      int f4 = tid + it * 256;
      int r = f4 >> 3, o4 = (f4 & 7) * 4;
      float4 v = *(const float4*)(qbase + r * 32 + o4);
      Qt_s[o4 + 0][r] = v.x; Qt_s[o4 + 1][r] = v.y; Qt_s[o4 + 2][r] = v.z; Qt_s[o4 + 3][r] = v.w;
    }
  }
  const float* vbase = qkv + (size_t)(b * 2048) * 1024 + 512 + h * 64;
  const float* kbh = karr + ((size_t)((b * 8 + h) * 2048)) * 32;

  for (int kt = 0; kt <= qt; ++kt) {
    __syncthreads();
    const float* kbase = kbh + (size_t)(kt * 64) * 32;
#pragma unroll
    for (int it = 0; it < 2; ++it) {
      int f4 = tid + it * 256;
      int r = f4 >> 3, o4 = (f4 & 7) * 4;
      float4 v = *(const float4*)(kbase + r * 32 + o4);
      Kt_s[o4 + 0][r] = v.x; Kt_s[o4 + 1][r] = v.y; Kt_s[o4 + 2][r] = v.z; Kt_s[o4 + 3][r] = v.w;
    }
#pragma unroll
    for (int it = 0; it < 4; ++it) {
      int f4 = tid + it * 256;
      int r = f4 >> 4, c4 = (f4 & 15) * 4;
      *(float4*)&Vs[r][c4] = *(const float4*)(vbase + (size_t)(kt * 64 + r) * 1024 + c4);
    }
    __syncthreads();

    float s[4][4] = {};
#pragma unroll
    for (int o = 0; o < 32; o++) {
      float4 qv = *(const float4*)&Qt_s[o][tr << 2];
      float4 kv = *(const float4*)&Kt_s[o][tc << 2];
      float qa[4] = {qv.x, qv.y, qv.z, qv.w};
      float ka[4] = {kv.x, kv.y, kv.z, kv.w};
#pragma unroll
      for (int i = 0; i < 4; i++)
#pragma unroll
        for (int j = 0; j < 4; j++) s[i][j] = fmaf(qa[i], ka[j], s[i][j]);
    }
    if (kt == qt) {
#pragma unroll
      for (int i = 0; i < 4; i++)
#pragma unroll
        for (int j = 0; j < 4; j++)
          if ((tc << 2) + j > (tr << 2) + i) s[i][j] = -1e30f;
    }

#pragma unroll
    for (int i = 0; i < 4; i++) {
      float pm = fmaxf(fmaxf(s[i][0], s[i][1]), fmaxf(s[i][2], s[i][3]));
#pragma unroll
      for (int mk = 1; mk < 16; mk <<= 1) pm = fmaxf(pm, __shfl_xor(pm, mk, 64));
      float mnew = fmaxf(m_i[i], pm);
      float alpha = __expf(m_i[i] - mnew);
      m_i[i] = mnew;
      l_i[i] *= alpha;
#pragma unroll
      for (int j = 0; j < 4; j++) acc[i][j] *= alpha;
      float p0 = __expf(s[i][0] - mnew), p1 = __expf(s[i][1] - mnew);
      float p2 = __expf(s[i][2] - mnew), p3 = __expf(s[i][3] - mnew);
      float psum = p0 + p1 + p2 + p3;
#pragma unroll
      for (int mk = 1; mk < 16; mk <<= 1) psum += __shfl_xor(psum, mk, 64);
      l_i[i] += psum;
      *(float4*)&Ps[(tr << 2) + i][tc << 2] = make_float4(p0, p1, p2, p3);
    }
    __syncthreads();

#pragma unroll 4
    for (int c4 = 0; c4 < 16; c4++) {
      float p[4][4];
#pragma unroll
      for (int i = 0; i < 4; i++) {
        float4 pv = *(const float4*)&Ps[(tr << 2) + i][c4 << 2];
        p[i][0] = pv.x; p[i][1] = pv.y; p[i][2] = pv.z; p[i][3] = pv.w;
      }
#pragma unroll
      for (int cc = 0; cc < 4; cc++) {
        float4 vv = *(const float4*)&Vs[(c4 << 2) + cc][tc << 2];
        float va[4] = {vv.x, vv.y, vv.z, vv.w};
#pragma unroll
        for (int i = 0; i < 4; i++)
#pragma unroll
          for (int j = 0; j < 4; j++) acc[i][j] = fmaf(p[i][cc], va[j], acc[i][j]);
      }
    }
  }

  float* yb = y + ((size_t)((b * 8 + h) * 2048 + qt * 64)) * 64;
#pragma unroll
  for (int i = 0; i < 4; i++) {
    float inv = 1.f / l_i[i];
    *(float4*)&yb[((tr << 2) + i) * 64 + (tc << 2)] =
        make_float4(acc[i][0] * inv, acc[i][1] * inv, acc[i][2] * inv, acc[i][3] * inv);
  }
}

// ---------------- self-align correction + permute to (b,t,512) bf16; one wave per row ----------------
__global__ __launch_bounds__(256) void align_correct(const float* __restrict__ y, const float* __restrict__ qkv,
                                                     u16* __restrict__ y2b) {
  int ridx = blockIdx.x * 4 + (threadIdx.x >> 6);
  int lane = threadIdx.x & 63;
  int t = ridx & 2047, h = (ridx >> 11) & 7, b = ridx >> 14;
  float yv = y[(size_t)ridx * 64 + lane];
  float vv = qkv[(size_t)(b * 2048 + t) * 1024 + 512 + h * 64 + lane];
  float ss = vv * vv;
#pragma unroll
  for (int mk = 1; mk < 64; mk <<= 1) ss += __shfl_xor(ss, mk, 64);
  float vn = vv / fmaxf(sqrtf(ss), 1e-12f);
  float d = yv * vn;
#pragma unroll
  for (int mk = 1; mk < 64; mk <<= 1) d += __shfl_xor(d, mk, 64);
  y2b[(size_t)(b * 2048 + t) * 512 + h * 64 + lane] = f2b(yv - d * vn);
}

// ---------------- LayerNorm (bf16 out) / RMSNorm (fp32 out): one wave per 512-row ----------------
template <bool RMS>
__global__ __launch_bounds__(256) void norm_kernel(const float* __restrict__ in, const float* __restrict__ g,
                                                   const float* __restrict__ bglob, float* __restrict__ outf,
                                                   u16* __restrict__ outb) {
  int row = blockIdx.x * 4 + (threadIdx.x >> 6);
  int lane = threadIdx.x & 63;
  const float* rp = in + (size_t)row * 512 + lane * 8;
  float4 a = *(const float4*)rp;
  float4 b = *(const float4*)(rp + 4);
  float v[8] = {a.x, a.y, a.z, a.w, b.x, b.y, b.z, b.w};
  float mean = 0.f, inv;
  if (!RMS) {
    float s = 0.f;
#pragma unroll
    for (int e = 0; e < 8; e++) s += v[e];
#pragma unroll
    for (int mk = 1; mk < 64; mk <<= 1) s += __shfl_xor(s, mk, 64);
    mean = s * (1.f / 512.f);
    float vs = 0.f;
#pragma unroll
    for (int e = 0; e < 8; e++) { float d = v[e] - mean; vs = fmaf(d, d, vs); }
#pragma unroll
    for (int mk = 1; mk < 64; mk <<= 1) vs += __shfl_xor(vs, mk, 64);
    inv = rsqrtf(vs * (1.f / 512.f) + 1e-5f);
  } else {
    float vs = 0.f;
#pragma unroll
    for (int e = 0; e < 8; e++) vs = fmaf(v[e], v[e], vs);
#pragma unroll
    for (int mk = 1; mk < 64; mk <<= 1) vs += __shfl_xor(vs, mk, 64);
    inv = rsqrtf(vs * (1.f / 512.f) + 1e-6f);
  }
  if (!RMS) {
    int c0 = lane * 8;
    u16* op = outb + (size_t)row * 512 + c0;
    ushort4 o1, o2;
    o1.x = f2b((v[0] - mean) * inv * g[c0 + 0] + bglob[c0 + 0]);
    o1.y = f2b((v[1] - mean) * inv * g[c0 + 1] + bglob[c0 + 1]);
    o1.z = f2b((v[2] - mean) * inv * g[c0 + 2] + bglob[c0 + 2]);
    o1.w = f2b((v[3] - mean) * inv * g[c0 + 3] + bglob[c0 + 3]);
    o2.x = f2b((v[4] - mean) * inv * g[c0 + 4] + bglob[c0 + 4]);
    o2.y = f2b((v[5] - mean) * inv * g[c0 + 5] + bglob[c0 + 5]);
    o2.z = f2b((v[6] - mean) * inv * g[c0 + 6] + bglob[c0 + 6]);
    o2.w = f2b((v[7] - mean) * inv * g[c0 + 7] + bglob[c0 + 7]);
    *(ushort4*)op = o1;
    *(ushort4*)(op + 4) = o2;
  } else {
    float* op = outf + (size_t)row * 512 + lane * 8;
    *(float4*)op = make_float4(v[0] * inv, v[1] * inv, v[2] * inv, v[3] * inv);
    *(float4*)(op + 4) = make_float4(v[4] * inv, v[5] * inv, v[6] * inv, v[7] * inv);
  }
}

// ---------------- final 512->32 projection + softplus temp + tanh ----------------
__global__ __launch_bounds__(256) void final_kernel(const float* __restrict__ r, const float* __restrict__ wout,
                                                    const float* __restrict__ ct, float* __restrict__ z) {
  int tok = blockIdx.x * 8 + (threadIdx.x >> 5);
  int n = threadIdx.x & 31;
  const float* rr = r + (size_t)tok * 512;
  const float* w = wout + (size_t)n * 512;
  float acc = 0.f;
  for (int d = 0; d < 512; d += 4) {
    float4 rv = *(const float4*)(rr + d);
    float4 wv = *(const float4*)(w + d);
    acc = fmaf(rv.x, wv.x, acc);
    acc = fmaf(rv.y, wv.y, acc);
    acc = fmaf(rv.z, wv.z, acc);
    acc = fmaf(rv.w, wv.w, acc);
  }
  float c = ct[n];
  float sp = (c > 20.f) ? c : log1pf(__expf(c));
  z[(size_t)tok * 32 + n] = tanhf(acc / (sp + 1e-4f));
}

extern "C" void kernel_launch(void* const* d_in, const int* in_sizes, int n_in,
                              void* d_out, int out_size, void* d_ws, size_t ws_size,
                              hipStream_t stream) {
  const float* x = (const float*)d_in[0];
  const float* qp = (const float*)d_in[1];
  const float* kp = (const float*)d_in[2];
  const float* wv = (const float*)d_in[3];
  const float* wpr = (const float*)d_in[4];
  const float* qg = (const float*)d_in[5];
  const float* w0 = (const float*)d_in[6];
  const float* g1 = (const float*)d_in[7];
  const float* b1 = (const float*)d_in[8];
  const float* w1 = (const float*)d_in[9];
  const float* g2 = (const float*)d_in[10];
  const float* b2 = (const float*)d_in[11];
  const float* w2 = (const float*)d_in[12];
  const float* wout = (const float*)d_in[13];
  const float* ct = (const float*)d_in[14];
  float* z = (float*)d_out;

  float* ws = (float*)d_ws;
  const size_t MEG = 1024 * 1024;
  float* A_QKV = ws;                       // 4M fp32: qkv; later he0 (2M) and rms out (2M)
  float* A_Q = ws + 4 * MEG;               // 1M fp32
  float* A_K = ws + 5 * MEG;               // 1M fp32; [4M..6M) later reused as he2 fp32
  float* A_HE2 = ws + 4 * MEG;             // alias
  float* A_Y = ws + 6 * MEG;               // 2M fp32: attn y; later he1
  float* A_H = ws + 8 * MEG;               // 2M fp32: h
  u16* A_Y2b = (u16*)(ws + 10 * MEG);      // 2M u16 = [10M..11M)
  u16* A_Hb = (u16*)(ws + 11 * MEG);       // [11M..12M)
  u16* A_LNb = (u16*)(ws + 12 * MEG);      // [12M..13M)
  u16* XB = (u16*)(ws + 13 * MEG);         // [13M..14M)
  u16* WCATb = (u16*)(ws + 14 * MEG);      // 1024*512 u16 = [14M..14.25M)
  u16* WPRb = WCATb + 524288;              // 512*512 u16 each
  u16* W0b = WPRb + 262144;
  u16* W1b = W0b + 262144;
  u16* W2b = W1b + 262144;

  hipLaunchKernelGGL(cast_x, dim3(2048), dim3(256), 0, stream, (const float4*)x, (ushort4*)XB);
  hipLaunchKernelGGL(cast_w4, dim3(1024), dim3(256), 0, stream, wpr, w0, w1, w2, WPRb, W0b, W1b, W2b);
  hipLaunchKernelGGL(build_wcat, dim3(2048), dim3(256), 0, stream, qp, kp, wv, WCATb);
  // qkv = x @ Wcat^T
  hipLaunchKernelGGL((mgemm<0, false>), dim3(16, 64), dim3(256), 0, stream, XB, WCATb,
                     (const float*)nullptr, A_QKV, (u16*)nullptr, 1024);
  hipLaunchKernelGGL(rope_kernel, dim3(2048), dim3(256), 0, stream, A_QKV, qg, A_Q, A_K);
  hipLaunchKernelGGL(attn_kernel, dim3(512), dim3(256), 0, stream, A_Q, A_K, A_QKV, A_Y);
  hipLaunchKernelGGL(align_correct, dim3(8192), dim3(256), 0, stream, A_Y, A_QKV, A_Y2b);
  // h = y2 @ wpr^T + x   (dual store fp32+bf16)
  hipLaunchKernelGGL((mgemm<1, true>), dim3(8, 64), dim3(256), 0, stream, A_Y2b, WPRb, x, A_H, A_Hb, 512);
  // he0 = h @ w0^T
  hipLaunchKernelGGL((mgemm<0, false>), dim3(8, 64), dim3(256), 0, stream, A_Hb, W0b,
                     (const float*)nullptr, A_QKV, (u16*)nullptr, 512);
  hipLaunchKernelGGL((norm_kernel<false>), dim3(1024), dim3(256), 0, stream, A_QKV, g1, b1,
                     (float*)nullptr, A_LNb);
  // he1 = h + silu(ln1 @ w1^T)
  hipLaunchKernelGGL((mgemm<2, false>), dim3(8, 64), dim3(256), 0, stream, A_LNb, W1b, A_H, A_Y,
                     (u16*)nullptr, 512);
  hipLaunchKernelGGL((norm_kernel<false>), dim3(1024), dim3(256), 0, stream, A_Y, g2, b2,
                     (float*)nullptr, A_LNb);
  // he2 = he1 + silu(ln2 @ w2^T)
  hipLaunchKernelGGL((mgemm<2, false>), dim3(8, 64), dim3(256), 0, stream, A_LNb, W2b, A_Y, A_HE2,
                     (u16*)nullptr, 512);
  hipLaunchKernelGGL((norm_kernel<true>), dim3(1024), dim3(256), 0, stream, A_HE2,
                     (const float*)nullptr, (const float*)nullptr, A_QKV, (u16*)nullptr);
  hipLaunchKernelGGL(final_kernel, dim3(512), dim3(256), 0, stream, A_QKV, wout, ct, z);
}

// Round 5
// 281.328 us; speedup vs baseline: 2.0791x; 1.2550x over previous
//
#include <hip/hip_runtime.h>
#include <math.h>

typedef unsigned short u16;
typedef __attribute__((ext_vector_type(8))) short short8;
typedef __attribute__((ext_vector_type(4))) float floatx4;

__device__ __forceinline__ float b2f(u16 u) { return __uint_as_float(((unsigned)u) << 16); }
__device__ __forceinline__ u16 f2b(float f) {
  unsigned u = __float_as_uint(f);
  return (u16)((u + 0x7fffu + ((u >> 16) & 1u)) >> 16);
}

// ---------------- cast fp32 -> bf16, 4 elems/thread (524288 float4s -> grid 2048) ----------------
__global__ __launch_bounds__(256) void cast_x(const float4* __restrict__ src, ushort4* __restrict__ dst) {
  int i = blockIdx.x * 256 + threadIdx.x;
  float4 v = src[i];
  ushort4 o; o.x = f2b(v.x); o.y = f2b(v.y); o.z = f2b(v.z); o.w = f2b(v.w);
  dst[i] = o;
}

// fused cast of the four 512x512 weights
__global__ __launch_bounds__(256) void cast_w4(const float* __restrict__ s0, const float* __restrict__ s1,
                                               const float* __restrict__ s2, const float* __restrict__ s3,
                                               u16* __restrict__ d0, u16* __restrict__ d1,
                                               u16* __restrict__ d2, u16* __restrict__ d3) {
  int i = blockIdx.x * 256 + threadIdx.x;  // 262144 float4s total
  int sel = i >> 16, j = i & 65535;
  const float* s = sel == 0 ? s0 : sel == 1 ? s1 : sel == 2 ? s2 : s3;
  u16* d = sel == 0 ? d0 : sel == 1 ? d1 : sel == 2 ? d2 : d3;
  float4 v = ((const float4*)s)[j];
  ushort4 o; o.x = f2b(v.x); o.y = f2b(v.y); o.z = f2b(v.z); o.w = f2b(v.w);
  ((ushort4*)d)[j] = o;
}

// ---------------- build Wcat (1024 x 512) bf16: rows = [q(256) | k(256) | v(512)] ----------------
__global__ __launch_bounds__(256) void build_wcat(const float* __restrict__ qp, const float* __restrict__ kp,
                                                  const float* __restrict__ wv, u16* __restrict__ wcat) {
  int i = blockIdx.x * 256 + threadIdx.x;  // 0..524287
  int d = i & 511, c = i >> 9;
  float v;
  if (c < 512) {
    int hh = c >> 5, o = c & 31;
    const float* src = (hh < 8) ? qp : kp;
    int h = hh & 7;
    v = src[(h * 512 + d) * 32 + o];
  } else {
    v = wv[(c - 512) * 512 + d];
  }
  wcat[i] = f2b(v);
}

// ---------------- bf16 MFMA GEMM: C[M x N] = A[M x 512] @ B^T (B: N x 512), bf16 in, fp32 acc ----
// EPI: 0 plain, 1 +X, 2 X + silu(acc). X fp32 stride 512. DUAL: also store bf16 copy.
template <int EPI, bool DUAL>
__global__ __launch_bounds__(256) void mgemm(const u16* __restrict__ A, const u16* __restrict__ Bw,
                                             const float* __restrict__ X, float* __restrict__ C,
                                             u16* __restrict__ Cb, int N) {
  __shared__ u16 As[64][40];
  __shared__ u16 Bs[64][40];
  const int tid = threadIdx.x;
  const int bm = blockIdx.y, bn = blockIdx.x;
  const int lane = tid & 63, wave = tid >> 6;
  const int wm = wave >> 1, wn = wave & 1;
  const int quad = lane >> 4, l16 = lane & 15;
  const int sr = tid >> 2;
  const int sk = (tid & 3) << 3;
  floatx4 acc[2][2] = {};
  const u16* Ap = A + (size_t)(bm * 64 + sr) * 512 + sk;
  const u16* Bp = Bw + (size_t)(bn * 64 + sr) * 512 + sk;
  for (int k0 = 0; k0 < 512; k0 += 32) {
    uint4 av = *(const uint4*)(Ap + k0);
    uint4 bv = *(const uint4*)(Bp + k0);
    __syncthreads();
    *(uint4*)&As[sr][sk] = av;
    *(uint4*)&Bs[sr][sk] = bv;
    __syncthreads();
    short8 a0 = *(const short8*)&As[wm * 32 + l16][quad * 8];
    short8 a1 = *(const short8*)&As[wm * 32 + 16 + l16][quad * 8];
    short8 b0 = *(const short8*)&Bs[wn * 32 + l16][quad * 8];
    short8 b1 = *(const short8*)&Bs[wn * 32 + 16 + l16][quad * 8];
    acc[0][0] = __builtin_amdgcn_mfma_f32_16x16x32_bf16(a0, b0, acc[0][0], 0, 0, 0);
    acc[0][1] = __builtin_amdgcn_mfma_f32_16x16x32_bf16(a0, b1, acc[0][1], 0, 0, 0);
    acc[1][0] = __builtin_amdgcn_mfma_f32_16x16x32_bf16(a1, b0, acc[1][0], 0, 0, 0);
    acc[1][1] = __builtin_amdgcn_mfma_f32_16x16x32_bf16(a1, b1, acc[1][1], 0, 0, 0);
  }
#pragma unroll
  for (int mt = 0; mt < 2; mt++)
#pragma unroll
    for (int r = 0; r < 4; r++) {
      int row = bm * 64 + wm * 32 + mt * 16 + quad * 4 + r;
#pragma unroll
      for (int nt = 0; nt < 2; nt++) {
        int col = bn * 64 + wn * 32 + nt * 16 + l16;
        float v = acc[mt][nt][r];
        if (EPI == 1) {
          v += X[(size_t)row * 512 + col];
        } else if (EPI == 2) {
          float xv = X[(size_t)row * 512 + col];
          v = xv + v / (1.f + __expf(-v));
        }
        C[(size_t)row * N + col] = v;
        if (DUAL) Cb[(size_t)row * N + col] = f2b(v);
      }
    }
}

// ---------------- RoPE + gain + score-scale fold; scatter bf16 q,k -> (b,h,t,32) ----------------
__global__ __launch_bounds__(256) void rope_kernel(const float* __restrict__ qkv, const float* __restrict__ qgain,
                                                   u16* __restrict__ qr, u16* __restrict__ kr) {
  int gid = blockIdx.x * 256 + threadIdx.x;  // B*H*T*16 = 524288
  int o = gid & 15;
  int t = (gid >> 4) & 2047;
  int h = (gid >> 15) & 7;
  int b = gid >> 18;
  const float* row = qkv + (size_t)(b * 2048 + t) * 1024;
  float freq = powf(10000.f, -(float)o / 16.f);
  float ang = (float)t * freq;
  float s, c;
  sincosf(ang, &s, &c);
  float g = qgain[h] * 0.17677669529663687f;  // gain * 1/sqrt(32)
  int qb = h * 32;
  float q0 = row[qb + o], q1 = row[qb + o + 16];
  float k0 = row[256 + qb + o], k1 = row[256 + qb + o + 16];
  u16* qo = qr + ((size_t)((b * 8 + h) * 2048 + t)) * 32;
  u16* ko = kr + ((size_t)((b * 8 + h) * 2048 + t)) * 32;
  qo[o] = f2b((q0 * c - q1 * s) * g);
  qo[o + 16] = f2b((q1 * c + q0 * s) * g);
  ko[o] = f2b(k0 * c - k1 * s);
  ko[o + 16] = f2b(k1 * c + k0 * s);
}

// ---------------- V transpose: qkv fp32 (b,t,1024)[v part] -> Vt bf16 (b,h,dv=64,T) ----------------
__global__ __launch_bounds__(256) void vtrans(const float* __restrict__ qkv, u16* __restrict__ Vt) {
  const int bh = blockIdx.y, tt = blockIdx.x;
  const int b = bh >> 3, h = bh & 7;
  __shared__ u16 Ts[64][72];
  const int tid = threadIdx.x;
  const int r = tid >> 2, q = tid & 3;
  const float* src = qkv + ((size_t)(b * 2048 + tt * 64 + r)) * 1024 + 512 + h * 64 + q * 16;
#pragma unroll
  for (int j = 0; j < 4; j++) {
    float4 v = *(const float4*)(src + j * 4);
    Ts[q * 16 + j * 4 + 0][r] = f2b(v.x);
    Ts[q * 16 + j * 4 + 1][r] = f2b(v.y);
    Ts[q * 16 + j * 4 + 2][r] = f2b(v.z);
    Ts[q * 16 + j * 4 + 3][r] = f2b(v.w);
  }
  __syncthreads();
  u16* dst = Vt + ((size_t)(bh * 64 + r)) * 2048 + tt * 64 + q * 16;
  *(uint4*)dst = *(const uint4*)&Ts[r][q * 16];
  *(uint4*)(dst + 8) = *(const uint4*)&Ts[r][q * 16 + 8];
}

// ---------------- MFMA causal flash attention: block = (b,h,qtile of 64), balanced remap --------
__global__ __launch_bounds__(256) void attn_mfma(const u16* __restrict__ Qb, const u16* __restrict__ Kb,
                                                 const u16* __restrict__ Vt, float* __restrict__ y) {
  const int bi = blockIdx.x;
  const int bh = bi & 15;
  const int q0i = (bi >> 4) & 15;
  const int qt = (bi >> 8) ? (31 - q0i) : q0i;
  const int tid = threadIdx.x;
  const int w = tid >> 6, lane = tid & 63, quad = lane >> 4, l16 = lane & 15;
  __shared__ u16 Vts[64][72];     // [dv][k-local], 144B rows (16B aligned, 2-way max)
  __shared__ u16 Ps[4][16][72];   // per-wave P strip [m][k-local]

  // Q A-frag lives in registers for the whole kernel
  short8 qfrag = *(const short8*)(Qb + ((size_t)(bh * 2048 + qt * 64 + w * 16 + l16)) * 32 + quad * 8);

  floatx4 o_acc[4] = {};
  float m_i[4], l_i[4];
#pragma unroll
  for (int i = 0; i < 4; i++) { m_i[i] = -INFINITY; l_i[i] = 0.f; }

  const u16* Kbase = Kb + (size_t)bh * 2048 * 32;
  const u16* Vtb = Vt + (size_t)bh * 64 * 2048;

  for (int kt = 0; kt <= qt; ++kt) {
    __syncthreads();  // protect Vts reuse
    {
      int vr = tid >> 2, vc = (tid & 3) << 4;
      const u16* src = Vtb + (size_t)vr * 2048 + kt * 64 + vc;
      *(uint4*)&Vts[vr][vc] = *(const uint4*)src;
      *(uint4*)&Vts[vr][vc + 8] = *(const uint4*)(src + 8);
    }
    __syncthreads();

    // S = Q K^T : one MFMA per 16-col chunk (K dim = 32 exactly)
    floatx4 s_acc[4];
#pragma unroll
    for (int nt = 0; nt < 4; nt++) {
      short8 kf = *(const short8*)(Kbase + (size_t)(kt * 64 + nt * 16 + l16) * 32 + quad * 8);
      floatx4 z = {0.f, 0.f, 0.f, 0.f};
      s_acc[nt] = __builtin_amdgcn_mfma_f32_16x16x32_bf16(qfrag, kf, z, 0, 0, 0);
    }

    // online softmax per m-row (C-layout: row = quad*4+r, col = nt*16+l16)
#pragma unroll
    for (int r = 0; r < 4; r++) {
      int mloc = w * 16 + quad * 4 + r;  // row within 64-row q-tile
      float sv[4];
#pragma unroll
      for (int nt = 0; nt < 4; nt++) {
        sv[nt] = s_acc[nt][r];
        if (kt == qt && (nt * 16 + l16) > mloc) sv[nt] = -1e30f;
      }
      float pm = fmaxf(fmaxf(sv[0], sv[1]), fmaxf(sv[2], sv[3]));
#pragma unroll
      for (int mk = 1; mk < 16; mk <<= 1) pm = fmaxf(pm, __shfl_xor(pm, mk, 64));
      float mnew = fmaxf(m_i[r], pm);
      float alpha = __expf(m_i[r] - mnew);
      m_i[r] = mnew;
      float p0 = __expf(sv[0] - mnew), p1 = __expf(sv[1] - mnew);
      float p2 = __expf(sv[2] - mnew), p3 = __expf(sv[3] - mnew);
      float psum = p0 + p1 + p2 + p3;
#pragma unroll
      for (int mk = 1; mk < 16; mk <<= 1) psum += __shfl_xor(psum, mk, 64);
      l_i[r] = l_i[r] * alpha + psum;
#pragma unroll
      for (int nt = 0; nt < 4; nt++) o_acc[nt][r] *= alpha;
      int mr = quad * 4 + r;
      Ps[w][mr][0 * 16 + l16] = f2b(p0);
      Ps[w][mr][1 * 16 + l16] = f2b(p1);
      Ps[w][mr][2 * 16 + l16] = f2b(p2);
      Ps[w][mr][3 * 16 + l16] = f2b(p3);
    }

    // O += P @ V  (P via wave-private LDS round trip; V^T already in B-layout)
#pragma unroll
    for (int kc = 0; kc < 2; kc++) {
      short8 pf = *(const short8*)&Ps[w][l16][kc * 32 + quad * 8];
#pragma unroll
      for (int nt = 0; nt < 4; nt++) {
        short8 vf = *(const short8*)&Vts[nt * 16 + l16][kc * 32 + quad * 8];
        o_acc[nt] = __builtin_amdgcn_mfma_f32_16x16x32_bf16(pf, vf, o_acc[nt], 0, 0, 0);
      }
    }
  }

  float* yb = y + ((size_t)(bh * 2048 + qt * 64)) * 64;
#pragma unroll
  for (int r = 0; r < 4; r++) {
    float inv = 1.f / l_i[r];
    int row = w * 16 + quad * 4 + r;
#pragma unroll
    for (int nt = 0; nt < 4; nt++) yb[(size_t)row * 64 + nt * 16 + l16] = o_acc[nt][r] * inv;
  }
}

// ---------------- self-align correction + permute to (b,t,512) bf16; one wave per row ----------------
__global__ __launch_bounds__(256) void align_correct(const float* __restrict__ y, const float* __restrict__ qkv,
                                                     u16* __restrict__ y2b) {
  int ridx = blockIdx.x * 4 + (threadIdx.x >> 6);
  int lane = threadIdx.x & 63;
  int t = ridx & 2047, h = (ridx >> 11) & 7, b = ridx >> 14;
  float yv = y[(size_t)ridx * 64 + lane];
  float vv = qkv[(size_t)(b * 2048 + t) * 1024 + 512 + h * 64 + lane];
  float ss = vv * vv;
#pragma unroll
  for (int mk = 1; mk < 64; mk <<= 1) ss += __shfl_xor(ss, mk, 64);
  float vn = vv / fmaxf(sqrtf(ss), 1e-12f);
  float d = yv * vn;
#pragma unroll
  for (int mk = 1; mk < 64; mk <<= 1) d += __shfl_xor(d, mk, 64);
  y2b[(size_t)(b * 2048 + t) * 512 + h * 64 + lane] = f2b(yv - d * vn);
}

// ---------------- LayerNorm (bf16 out) / RMSNorm (fp32 out): one wave per 512-row ----------------
template <bool RMS>
__global__ __launch_bounds__(256) void norm_kernel(const float* __restrict__ in, const float* __restrict__ g,
                                                   const float* __restrict__ bglob, float* __restrict__ outf,
                                                   u16* __restrict__ outb) {
  int row = blockIdx.x * 4 + (threadIdx.x >> 6);
  int lane = threadIdx.x & 63;
  const float* rp = in + (size_t)row * 512 + lane * 8;
  float4 a = *(const float4*)rp;
  float4 b = *(const float4*)(rp + 4);
  float v[8] = {a.x, a.y, a.z, a.w, b.x, b.y, b.z, b.w};
  float mean = 0.f, inv;
  if (!RMS) {
    float s = 0.f;
#pragma unroll
    for (int e = 0; e < 8; e++) s += v[e];
#pragma unroll
    for (int mk = 1; mk < 64; mk <<= 1) s += __shfl_xor(s, mk, 64);
    mean = s * (1.f / 512.f);
    float vs = 0.f;
#pragma unroll
    for (int e = 0; e < 8; e++) { float d = v[e] - mean; vs = fmaf(d, d, vs); }
#pragma unroll
    for (int mk = 1; mk < 64; mk <<= 1) vs += __shfl_xor(vs, mk, 64);
    inv = rsqrtf(vs * (1.f / 512.f) + 1e-5f);
  } else {
    float vs = 0.f;
#pragma unroll
    for (int e = 0; e < 8; e++) vs = fmaf(v[e], v[e], vs);
#pragma unroll
    for (int mk = 1; mk < 64; mk <<= 1) vs += __shfl_xor(vs, mk, 64);
    inv = rsqrtf(vs * (1.f / 512.f) + 1e-6f);
  }
  if (!RMS) {
    int c0 = lane * 8;
    u16* op = outb + (size_t)row * 512 + c0;
    ushort4 o1, o2;
    o1.x = f2b((v[0] - mean) * inv * g[c0 + 0] + bglob[c0 + 0]);
    o1.y = f2b((v[1] - mean) * inv * g[c0 + 1] + bglob[c0 + 1]);
    o1.z = f2b((v[2] - mean) * inv * g[c0 + 2] + bglob[c0 + 2]);
    o1.w = f2b((v[3] - mean) * inv * g[c0 + 3] + bglob[c0 + 3]);
    o2.x = f2b((v[4] - mean) * inv * g[c0 + 4] + bglob[c0 + 4]);
    o2.y = f2b((v[5] - mean) * inv * g[c0 + 5] + bglob[c0 + 5]);
    o2.z = f2b((v[6] - mean) * inv * g[c0 + 6] + bglob[c0 + 6]);
    o2.w = f2b((v[7] - mean) * inv * g[c0 + 7] + bglob[c0 + 7]);
    *(ushort4*)op = o1;
    *(ushort4*)(op + 4) = o2;
  } else {
    float* op = outf + (size_t)row * 512 + lane * 8;
    *(float4*)op = make_float4(v[0] * inv, v[1] * inv, v[2] * inv, v[3] * inv);
    *(float4*)(op + 4) = make_float4(v[4] * inv, v[5] * inv, v[6] * inv, v[7] * inv);
  }
}

// ---------------- final 512->32 projection + softplus temp + tanh ----------------
__global__ __launch_bounds__(256) void final_kernel(const float* __restrict__ r, const float* __restrict__ wout,
                                                    const float* __restrict__ ct, float* __restrict__ z) {
  int tok = blockIdx.x * 8 + (threadIdx.x >> 5);
  int n = threadIdx.x & 31;
  const float* rr = r + (size_t)tok * 512;
  const float* w = wout + (size_t)n * 512;
  float acc = 0.f;
  for (int d = 0; d < 512; d += 4) {
    float4 rv = *(const float4*)(rr + d);
    float4 wv = *(const float4*)(w + d);
    acc = fmaf(rv.x, wv.x, acc);
    acc = fmaf(rv.y, wv.y, acc);
    acc = fmaf(rv.z, wv.z, acc);
    acc = fmaf(rv.w, wv.w, acc);
  }
  float c = ct[n];
  float sp = (c > 20.f) ? c : log1pf(__expf(c));
  z[(size_t)tok * 32 + n] = tanhf(acc / (sp + 1e-4f));
}

extern "C" void kernel_launch(void* const* d_in, const int* in_sizes, int n_in,
                              void* d_out, int out_size, void* d_ws, size_t ws_size,
                              hipStream_t stream) {
  const float* x = (const float*)d_in[0];
  const float* qp = (const float*)d_in[1];
  const float* kp = (const float*)d_in[2];
  const float* wv = (const float*)d_in[3];
  const float* wpr = (const float*)d_in[4];
  const float* qg = (const float*)d_in[5];
  const float* w0 = (const float*)d_in[6];
  const float* g1 = (const float*)d_in[7];
  const float* b1 = (const float*)d_in[8];
  const float* w1 = (const float*)d_in[9];
  const float* g2 = (const float*)d_in[10];
  const float* b2 = (const float*)d_in[11];
  const float* w2 = (const float*)d_in[12];
  const float* wout = (const float*)d_in[13];
  const float* ct = (const float*)d_in[14];
  float* z = (float*)d_out;

  float* ws = (float*)d_ws;
  const size_t MEG = 1024 * 1024;
  float* A_QKV = ws;                       // [0..4M) fp32 qkv; later he0 (2M) + rms out (2M)
  u16* A_Qb = (u16*)(ws + 4 * MEG);        // 1M u16 = [4M..4.5M)
  u16* A_Kb = (u16*)(ws + 4 * MEG + 524288);  // [4.5M..5M)
  u16* A_Vt = (u16*)(ws + 5 * MEG);        // 2M u16 = [5M..6M)
  float* A_HE2 = ws + 4 * MEG;             // alias (after attention done)
  float* A_Y = ws + 6 * MEG;               // 2M fp32: attn y; later he1
  float* A_H = ws + 8 * MEG;               // 2M fp32: h
  u16* A_Y2b = (u16*)(ws + 10 * MEG);      // [10M..11M)
  u16* A_Hb = (u16*)(ws + 11 * MEG);       // [11M..12M)
  u16* A_LNb = (u16*)(ws + 12 * MEG);      // [12M..13M)
  u16* XB = (u16*)(ws + 13 * MEG);         // [13M..14M)
  u16* WCATb = (u16*)(ws + 14 * MEG);      // [14M..14.25M)
  u16* WPRb = WCATb + 524288;
  u16* W0b = WPRb + 262144;
  u16* W1b = W0b + 262144;
  u16* W2b = W1b + 262144;

  hipLaunchKernelGGL(cast_x, dim3(2048), dim3(256), 0, stream, (const float4*)x, (ushort4*)XB);
  hipLaunchKernelGGL(cast_w4, dim3(1024), dim3(256), 0, stream, wpr, w0, w1, w2, WPRb, W0b, W1b, W2b);
  hipLaunchKernelGGL(build_wcat, dim3(2048), dim3(256), 0, stream, qp, kp, wv, WCATb);
  // qkv = x @ Wcat^T
  hipLaunchKernelGGL((mgemm<0, false>), dim3(16, 64), dim3(256), 0, stream, XB, WCATb,
                     (const float*)nullptr, A_QKV, (u16*)nullptr, 1024);
  hipLaunchKernelGGL(rope_kernel, dim3(2048), dim3(256), 0, stream, A_QKV, qg, A_Qb, A_Kb);
  hipLaunchKernelGGL(vtrans, dim3(32, 16), dim3(256), 0, stream, A_QKV, A_Vt);
  hipLaunchKernelGGL(attn_mfma, dim3(512), dim3(256), 0, stream, A_Qb, A_Kb, A_Vt, A_Y);
  hipLaunchKernelGGL(align_correct, dim3(8192), dim3(256), 0, stream, A_Y, A_QKV, A_Y2b);
  // h = y2 @ wpr^T + x   (dual store fp32+bf16)
  hipLaunchKernelGGL((mgemm<1, true>), dim3(8, 64), dim3(256), 0, stream, A_Y2b, WPRb, x, A_H, A_Hb, 512);
  // he0 = h @ w0^T
  hipLaunchKernelGGL((mgemm<0, false>), dim3(8, 64), dim3(256), 0, stream, A_Hb, W0b,
                     (const float*)nullptr, A_QKV, (u16*)nullptr, 512);
  hipLaunchKernelGGL((norm_kernel<false>), dim3(1024), dim3(256), 0, stream, A_QKV, g1, b1,
                     (float*)nullptr, A_LNb);
  // he1 = h + silu(ln1 @ w1^T)
  hipLaunchKernelGGL((mgemm<2, false>), dim3(8, 64), dim3(256), 0, stream, A_LNb, W1b, A_H, A_Y,
                     (u16*)nullptr, 512);
  hipLaunchKernelGGL((norm_kernel<false>), dim3(1024), dim3(256), 0, stream, A_Y, g2, b2,
                     (float*)nullptr, A_LNb);
  // he2 = he1 + silu(ln2 @ w2^T)
  hipLaunchKernelGGL((mgemm<2, false>), dim3(8, 64), dim3(256), 0, stream, A_LNb, W2b, A_Y, A_HE2,
                     (u16*)nullptr, 512);
  hipLaunchKernelGGL((norm_kernel<true>), dim3(1024), dim3(256), 0, stream, A_HE2,
                     (const float*)nullptr, (const float*)nullptr, A_QKV, (u16*)nullptr);
  hipLaunchKernelGGL(final_kernel, dim3(512), dim3(256), 0, stream, A_QKV, wout, ct, z);
}

// Round 6
// 240.019 us; speedup vs baseline: 2.4369x; 1.1721x over previous
//
#include <hip/hip_runtime.h>
#include <math.h>

typedef unsigned short u16;
typedef __attribute__((ext_vector_type(8))) short short8;
typedef __attribute__((ext_vector_type(4))) float floatx4;

__device__ __forceinline__ float b2f(u16 u) { return __uint_as_float(((unsigned)u) << 16); }
__device__ __forceinline__ u16 f2b(float f) {
  unsigned u = __float_as_uint(f);
  return (u16)((u + 0x7fffu + ((u >> 16) & 1u)) >> 16);
}

// ---------- fused prep: cast x -> bf16 | cast 4 weights | build Wcat ----------
__global__ __launch_bounds__(256) void prep_cast(const float* __restrict__ x, const float* __restrict__ wpr,
                                                 const float* __restrict__ w0, const float* __restrict__ w1,
                                                 const float* __restrict__ w2, const float* __restrict__ qp,
                                                 const float* __restrict__ kp, const float* __restrict__ wv,
                                                 u16* __restrict__ XB, u16* __restrict__ WPRb,
                                                 u16* __restrict__ W0b, u16* __restrict__ W1b,
                                                 u16* __restrict__ W2b, u16* __restrict__ wcat) {
  int bi = blockIdx.x, tid = threadIdx.x;
  if (bi < 2048) {                       // cast_x: 524288 float4s
    int i = bi * 256 + tid;
    float4 v = ((const float4*)x)[i];
    ushort4 o; o.x = f2b(v.x); o.y = f2b(v.y); o.z = f2b(v.z); o.w = f2b(v.w);
    ((ushort4*)XB)[i] = o;
  } else if (bi < 3072) {                // cast 4x 512x512 weights: 262144 float4s
    int i = (bi - 2048) * 256 + tid;
    int sel = i >> 16, j = i & 65535;
    const float* s = sel == 0 ? wpr : sel == 1 ? w0 : sel == 2 ? w1 : w2;
    u16* d = sel == 0 ? WPRb : sel == 1 ? W0b : sel == 2 ? W1b : W2b;
    float4 v = ((const float4*)s)[j];
    ushort4 o; o.x = f2b(v.x); o.y = f2b(v.y); o.z = f2b(v.z); o.w = f2b(v.w);
    ((ushort4*)d)[j] = o;
  } else {                               // build_wcat: 524288 elements
    int i = (bi - 3072) * 256 + tid;
    int d = i & 511, c = i >> 9;
    float v;
    if (c < 512) {
      int hh = c >> 5, o = c & 31;
      const float* src = (hh < 8) ? qp : kp;
      int h = hh & 7;
      v = src[(h * 512 + d) * 32 + o];
    } else {
      v = wv[(c - 512) * 512 + d];
    }
    wcat[i] = f2b(v);
  }
}

// ---------- bf16 MFMA GEMM: C[M x N] = A[M x 512] @ B^T, fp32 acc ----------
// EPI: 0 plain, 1 +X, 2 X + silu(acc). DUAL: also store bf16 copy.
template <int EPI, bool DUAL>
__global__ __launch_bounds__(256) void mgemm(const u16* __restrict__ A, const u16* __restrict__ Bw,
                                             const float* __restrict__ X, float* __restrict__ C,
                                             u16* __restrict__ Cb, int N) {
  __shared__ u16 As[64][40];
  __shared__ u16 Bs[64][40];
  const int tid = threadIdx.x;
  const int bm = blockIdx.y, bn = blockIdx.x;
  const int lane = tid & 63, wave = tid >> 6;
  const int wm = wave >> 1, wn = wave & 1;
  const int quad = lane >> 4, l16 = lane & 15;
  const int sr = tid >> 2;
  const int sk = (tid & 3) << 3;
  floatx4 acc[2][2] = {};
  const u16* Ap = A + (size_t)(bm * 64 + sr) * 512 + sk;
  const u16* Bp = Bw + (size_t)(bn * 64 + sr) * 512 + sk;
  for (int k0 = 0; k0 < 512; k0 += 32) {
    uint4 av = *(const uint4*)(Ap + k0);
    uint4 bv = *(const uint4*)(Bp + k0);
    __syncthreads();
    *(uint4*)&As[sr][sk] = av;
    *(uint4*)&Bs[sr][sk] = bv;
    __syncthreads();
    short8 a0 = *(const short8*)&As[wm * 32 + l16][quad * 8];
    short8 a1 = *(const short8*)&As[wm * 32 + 16 + l16][quad * 8];
    short8 b0 = *(const short8*)&Bs[wn * 32 + l16][quad * 8];
    short8 b1 = *(const short8*)&Bs[wn * 32 + 16 + l16][quad * 8];
    acc[0][0] = __builtin_amdgcn_mfma_f32_16x16x32_bf16(a0, b0, acc[0][0], 0, 0, 0);
    acc[0][1] = __builtin_amdgcn_mfma_f32_16x16x32_bf16(a0, b1, acc[0][1], 0, 0, 0);
    acc[1][0] = __builtin_amdgcn_mfma_f32_16x16x32_bf16(a1, b0, acc[1][0], 0, 0, 0);
    acc[1][1] = __builtin_amdgcn_mfma_f32_16x16x32_bf16(a1, b1, acc[1][1], 0, 0, 0);
  }
#pragma unroll
  for (int mt = 0; mt < 2; mt++)
#pragma unroll
    for (int r = 0; r < 4; r++) {
      int row = bm * 64 + wm * 32 + mt * 16 + quad * 4 + r;
#pragma unroll
      for (int nt = 0; nt < 2; nt++) {
        int col = bn * 64 + wn * 32 + nt * 16 + l16;
        float v = acc[mt][nt][r];
        if (EPI == 1) {
          v += X[(size_t)row * 512 + col];
        } else if (EPI == 2) {
          float xv = X[(size_t)row * 512 + col];
          v = xv + v / (1.f + __expf(-v));
        }
        C[(size_t)row * N + col] = v;
        if (DUAL) Cb[(size_t)row * N + col] = f2b(v);
      }
    }
}

// ---------- fused prep_attn: RoPE q,k -> bf16 (b,h,t,32) | V -> bf16 (b,h,64,T) ----------
__global__ __launch_bounds__(256) void prep_attn(const float* __restrict__ qkv, const float* __restrict__ qgain,
                                                 u16* __restrict__ qr, u16* __restrict__ kr,
                                                 u16* __restrict__ Vt) {
  const int bi = blockIdx.x, tid = threadIdx.x;
  if (bi < 2048) {  // RoPE: 524288 threads
    int gid = bi * 256 + tid;
    int o = gid & 15;
    int t = (gid >> 4) & 2047;
    int h = (gid >> 15) & 7;
    int b = gid >> 18;
    const float* row = qkv + (size_t)(b * 2048 + t) * 1024;
    float freq = powf(10000.f, -(float)o / 16.f);
    float ang = (float)t * freq;
    float s, c;
    sincosf(ang, &s, &c);
    float g = qgain[h] * 0.17677669529663687f;  // gain * 1/sqrt(32)
    int qb = h * 32;
    float q0 = row[qb + o], q1 = row[qb + o + 16];
    float k0 = row[256 + qb + o], k1 = row[256 + qb + o + 16];
    u16* qo = qr + ((size_t)((b * 8 + h) * 2048 + t)) * 32;
    u16* ko = kr + ((size_t)((b * 8 + h) * 2048 + t)) * 32;
    qo[o] = f2b((q0 * c - q1 * s) * g);
    qo[o + 16] = f2b((q1 * c + q0 * s) * g);
    ko[o] = f2b(k0 * c - k1 * s);
    ko[o + 16] = f2b(k1 * c + k0 * s);
  } else {  // V transpose: 512 blocks
    int idx = bi - 2048;
    const int tt = idx & 31, bh = idx >> 5;
    const int b = bh >> 3, h = bh & 7;
    __shared__ u16 Ts[64][72];
    const int r = tid >> 2, q = tid & 3;
    const float* src = qkv + ((size_t)(b * 2048 + tt * 64 + r)) * 1024 + 512 + h * 64 + q * 16;
#pragma unroll
    for (int j = 0; j < 4; j++) {
      float4 v = *(const float4*)(src + j * 4);
      Ts[q * 16 + j * 4 + 0][r] = f2b(v.x);
      Ts[q * 16 + j * 4 + 1][r] = f2b(v.y);
      Ts[q * 16 + j * 4 + 2][r] = f2b(v.z);
      Ts[q * 16 + j * 4 + 3][r] = f2b(v.w);
    }
    __syncthreads();
    u16* dst = Vt + ((size_t)(bh * 64 + r)) * 2048 + tt * 64 + q * 16;
    *(uint4*)dst = *(const uint4*)&Ts[r][q * 16];
    *(uint4*)(dst + 8) = *(const uint4*)&Ts[r][q * 16 + 8];
  }
}

// ---------- MFMA causal flash attention, no-max softmax, fused self-align ----------
__global__ __launch_bounds__(256) void attn_fused(const u16* __restrict__ Qb, const u16* __restrict__ Kb,
                                                  const u16* __restrict__ Vt, const float* __restrict__ qkv,
                                                  u16* __restrict__ y2b) {
  const int bi = blockIdx.x;
  const int bh = bi & 15;
  const int q0i = (bi >> 4) & 15;
  const int qt = (bi >> 8) ? (31 - q0i) : q0i;  // balance remap
  const int b = bh >> 3, h = bh & 7;
  const int tid = threadIdx.x;
  const int w = tid >> 6, lane = tid & 63, quad = lane >> 4, l16 = lane & 15;
  __shared__ u16 Vts[64][72];
  __shared__ u16 Ps[4][16][72];

  short8 qfrag = *(const short8*)(Qb + ((size_t)(bh * 2048 + qt * 64 + w * 16 + l16)) * 32 + quad * 8);
  floatx4 o_acc[4] = {};
  float l_part[4] = {0.f, 0.f, 0.f, 0.f};
  const u16* Kbase = Kb + (size_t)bh * 2048 * 32;
  const u16* Vtb = Vt + (size_t)bh * 64 * 2048;

  for (int kt = 0; kt <= qt; ++kt) {
    __syncthreads();
    {
      int vr = tid >> 2, vc = (tid & 3) << 4;
      const u16* src = Vtb + (size_t)vr * 2048 + kt * 64 + vc;
      *(uint4*)&Vts[vr][vc] = *(const uint4*)src;
      *(uint4*)&Vts[vr][vc + 8] = *(const uint4*)(src + 8);
    }
    __syncthreads();

    floatx4 s_acc[4];
#pragma unroll
    for (int nt = 0; nt < 4; nt++) {
      short8 kf = *(const short8*)(Kbase + (size_t)(kt * 64 + nt * 16 + l16) * 32 + quad * 8);
      floatx4 zz = {0.f, 0.f, 0.f, 0.f};
      s_acc[nt] = __builtin_amdgcn_mfma_f32_16x16x32_bf16(qfrag, kf, zz, 0, 0, 0);
    }
    const bool diag = (kt == qt);
#pragma unroll
    for (int r = 0; r < 4; r++) {
      int mloc = w * 16 + quad * 4 + r;
      float psum = 0.f;
#pragma unroll
      for (int nt = 0; nt < 4; nt++) {
        float p = __expf(s_acc[nt][r]);          // scores O(1): no max subtraction needed
        if (diag && (nt * 16 + l16) > mloc) p = 0.f;
        psum += p;
        Ps[w][quad * 4 + r][nt * 16 + l16] = f2b(p);
      }
      l_part[r] += psum;
    }
#pragma unroll
    for (int kc = 0; kc < 2; kc++) {
      short8 pf = *(const short8*)&Ps[w][l16][kc * 32 + quad * 8];
#pragma unroll
      for (int nt = 0; nt < 4; nt++) {
        short8 vf = *(const short8*)&Vts[nt * 16 + l16][kc * 32 + quad * 8];
        o_acc[nt] = __builtin_amdgcn_mfma_f32_16x16x32_bf16(pf, vf, o_acc[nt], 0, 0, 0);
      }
    }
  }

  // single softmax-denominator reduction after the loop
  float l_i[4];
#pragma unroll
  for (int r = 0; r < 4; r++) {
    float ls = l_part[r];
#pragma unroll
    for (int mk = 1; mk < 16; mk <<= 1) ls += __shfl_xor(ls, mk, 64);
    l_i[r] = ls;
  }

  // fused self-align correction + permute to (b,t,512) bf16
#pragma unroll
  for (int r = 0; r < 4; r++) {
    int row = w * 16 + quad * 4 + r;
    int tok = qt * 64 + row;
    float linv = 1.f / l_i[r];
    const float* vp = qkv + ((size_t)(b * 2048 + tok)) * 1024 + 512 + h * 64;
    float yv[4], vv[4];
    float ss = 0.f, dot = 0.f;
#pragma unroll
    for (int nt = 0; nt < 4; nt++) {
      yv[nt] = o_acc[nt][r] * linv;
      vv[nt] = vp[nt * 16 + l16];
      ss = fmaf(vv[nt], vv[nt], ss);
      dot = fmaf(yv[nt], vv[nt], dot);
    }
#pragma unroll
    for (int mk = 1; mk < 16; mk <<= 1) {
      ss += __shfl_xor(ss, mk, 64);
      dot += __shfl_xor(dot, mk, 64);
    }
    float nrm = fmaxf(sqrtf(ss), 1e-12f);
    float coef = dot / (nrm * nrm);
    u16* op = y2b + ((size_t)(b * 2048 + tok)) * 512 + h * 64;
#pragma unroll
    for (int nt = 0; nt < 4; nt++) op[nt * 16 + l16] = f2b(yv[nt] - coef * vv[nt]);
  }
}

// ---------- LayerNorm (bf16 out): one wave per 512-row ----------
__global__ __launch_bounds__(256) void ln_kernel(const float* __restrict__ in, const float* __restrict__ g,
                                                 const float* __restrict__ bglob, u16* __restrict__ outb) {
  int row = blockIdx.x * 4 + (threadIdx.x >> 6);
  int lane = threadIdx.x & 63;
  const float* rp = in + (size_t)row * 512 + lane * 8;
  float4 a = *(const float4*)rp;
  float4 b = *(const float4*)(rp + 4);
  float v[8] = {a.x, a.y, a.z, a.w, b.x, b.y, b.z, b.w};
  float s = 0.f;
#pragma unroll
  for (int e = 0; e < 8; e++) s += v[e];
#pragma unroll
  for (int mk = 1; mk < 64; mk <<= 1) s += __shfl_xor(s, mk, 64);
  float mean = s * (1.f / 512.f);
  float vs = 0.f;
#pragma unroll
  for (int e = 0; e < 8; e++) { float d = v[e] - mean; vs = fmaf(d, d, vs); }
#pragma unroll
  for (int mk = 1; mk < 64; mk <<= 1) vs += __shfl_xor(vs, mk, 64);
  float inv = rsqrtf(vs * (1.f / 512.f) + 1e-5f);
  int c0 = lane * 8;
  u16* op = outb + (size_t)row * 512 + c0;
  ushort4 o1, o2;
  o1.x = f2b((v[0] - mean) * inv * g[c0 + 0] + bglob[c0 + 0]);
  o1.y = f2b((v[1] - mean) * inv * g[c0 + 1] + bglob[c0 + 1]);
  o1.z = f2b((v[2] - mean) * inv * g[c0 + 2] + bglob[c0 + 2]);
  o1.w = f2b((v[3] - mean) * inv * g[c0 + 3] + bglob[c0 + 3]);
  o2.x = f2b((v[4] - mean) * inv * g[c0 + 4] + bglob[c0 + 4]);
  o2.y = f2b((v[5] - mean) * inv * g[c0 + 5] + bglob[c0 + 5]);
  o2.z = f2b((v[6] - mean) * inv * g[c0 + 6] + bglob[c0 + 6]);
  o2.w = f2b((v[7] - mean) * inv * g[c0 + 7] + bglob[c0 + 7]);
  *(ushort4*)op = o1;
  *(ushort4*)(op + 4) = o2;
}

// ---------- fused RMS + 512->32 projection + softplus temp + tanh ----------
__global__ __launch_bounds__(256) void final_rms(const float* __restrict__ he2, const float* __restrict__ wout,
                                                 const float* __restrict__ ct, float* __restrict__ z) {
  int tok = blockIdx.x * 8 + (threadIdx.x >> 5);
  int n = threadIdx.x & 31;
  const float* rr = he2 + (size_t)tok * 512;
  // rms over the row: each lane covers 4 float4s, reduce over the 32-lane group
  float ss = 0.f;
#pragma unroll
  for (int j = 0; j < 4; j++) {
    float4 v = ((const float4*)rr)[j * 32 + n];
    ss = fmaf(v.x, v.x, fmaf(v.y, v.y, fmaf(v.z, v.z, fmaf(v.w, v.w, ss))));
  }
#pragma unroll
  for (int mk = 1; mk < 32; mk <<= 1) ss += __shfl_xor(ss, mk, 64);
  float rinv = rsqrtf(ss * (1.f / 512.f) + 1e-6f);
  const float* w = wout + (size_t)n * 512;
  float acc = 0.f;
  for (int d = 0; d < 512; d += 4) {
    float4 rv = *(const float4*)(rr + d);
    float4 wv = *(const float4*)(w + d);
    acc = fmaf(rv.x, wv.x, acc);
    acc = fmaf(rv.y, wv.y, acc);
    acc = fmaf(rv.z, wv.z, acc);
    acc = fmaf(rv.w, wv.w, acc);
  }
  float c = ct[n];
  float sp = (c > 20.f) ? c : log1pf(__expf(c));
  z[(size_t)tok * 32 + n] = tanhf(acc * rinv / (sp + 1e-4f));
}

extern "C" void kernel_launch(void* const* d_in, const int* in_sizes, int n_in,
                              void* d_out, int out_size, void* d_ws, size_t ws_size,
                              hipStream_t stream) {
  const float* x = (const float*)d_in[0];
  const float* qp = (const float*)d_in[1];
  const float* kp = (const float*)d_in[2];
  const float* wv = (const float*)d_in[3];
  const float* wpr = (const float*)d_in[4];
  const float* qg = (const float*)d_in[5];
  const float* w0 = (const float*)d_in[6];
  const float* g1 = (const float*)d_in[7];
  const float* b1 = (const float*)d_in[8];
  const float* w1 = (const float*)d_in[9];
  const float* g2 = (const float*)d_in[10];
  const float* b2 = (const float*)d_in[11];
  const float* w2 = (const float*)d_in[12];
  const float* wout = (const float*)d_in[13];
  const float* ct = (const float*)d_in[14];
  float* z = (float*)d_out;

  float* ws = (float*)d_ws;
  const size_t MEG = 1024 * 1024;
  float* A_QKV = ws;                          // [0..4M) fp32 qkv; later he0
  u16* A_Qb = (u16*)(ws + 4 * MEG);           // [4M..4.5M)
  u16* A_Kb = (u16*)(ws + 4 * MEG + 524288);  // [4.5M..5M)
  u16* A_Vt = (u16*)(ws + 5 * MEG);           // [5M..6M)
  float* A_HE2 = ws + 4 * MEG;                // alias (after attention)
  float* A_Y = ws + 6 * MEG;                  // [6M..8M) he1 fp32
  float* A_H = ws + 8 * MEG;                  // [8M..10M) h fp32
  u16* A_Y2b = (u16*)(ws + 10 * MEG);         // [10M..11M)
  u16* A_Hb = (u16*)(ws + 11 * MEG);          // [11M..12M)
  u16* A_LNb = (u16*)(ws + 12 * MEG);         // [12M..13M)
  u16* XB = (u16*)(ws + 13 * MEG);            // [13M..14M)
  u16* WCATb = (u16*)(ws + 14 * MEG);         // [14M..14.25M)
  u16* WPRb = WCATb + 524288;
  u16* W0b = WPRb + 262144;
  u16* W1b = W0b + 262144;
  u16* W2b = W1b + 262144;

  hipLaunchKernelGGL(prep_cast, dim3(5120), dim3(256), 0, stream, x, wpr, w0, w1, w2, qp, kp, wv,
                     XB, WPRb, W0b, W1b, W2b, WCATb);
  hipLaunchKernelGGL((mgemm<0, false>), dim3(16, 64), dim3(256), 0, stream, XB, WCATb,
                     (const float*)nullptr, A_QKV, (u16*)nullptr, 1024);
  hipLaunchKernelGGL(prep_attn, dim3(2560), dim3(256), 0, stream, A_QKV, qg, A_Qb, A_Kb, A_Vt);
  hipLaunchKernelGGL(attn_fused, dim3(512), dim3(256), 0, stream, A_Qb, A_Kb, A_Vt, A_QKV, A_Y2b);
  // h = y2 @ wpr^T + x   (dual store fp32+bf16)
  hipLaunchKernelGGL((mgemm<1, true>), dim3(8, 64), dim3(256), 0, stream, A_Y2b, WPRb, x, A_H, A_Hb, 512);
  // he0 = h @ w0^T
  hipLaunchKernelGGL((mgemm<0, false>), dim3(8, 64), dim3(256), 0, stream, A_Hb, W0b,
                     (const float*)nullptr, A_QKV, (u16*)nullptr, 512);
  hipLaunchKernelGGL(ln_kernel, dim3(1024), dim3(256), 0, stream, A_QKV, g1, b1, A_LNb);
  // he1 = h + silu(ln1 @ w1^T)
  hipLaunchKernelGGL((mgemm<2, false>), dim3(8, 64), dim3(256), 0, stream, A_LNb, W1b, A_H, A_Y,
                     (u16*)nullptr, 512);
  hipLaunchKernelGGL(ln_kernel, dim3(1024), dim3(256), 0, stream, A_Y, g2, b2, A_LNb);
  // he2 = he1 + silu(ln2 @ w2^T)
  hipLaunchKernelGGL((mgemm<2, false>), dim3(8, 64), dim3(256), 0, stream, A_LNb, W2b, A_Y, A_HE2,
                     (u16*)nullptr, 512);
  hipLaunchKernelGGL(final_rms, dim3(512), dim3(256), 0, stream, A_HE2, wout, ct, z);
}

// Round 8
// 224.609 us; speedup vs baseline: 2.6041x; 1.0686x over previous
//
#include <hip/hip_runtime.h>
#include <math.h>

typedef unsigned short u16;
typedef __attribute__((ext_vector_type(8))) short short8;
typedef __attribute__((ext_vector_type(4))) float floatx4;

__device__ __forceinline__ float b2f(u16 u) { return __uint_as_float(((unsigned)u) << 16); }
__device__ __forceinline__ u16 f2b(float f) {
  unsigned u = __float_as_uint(f);
  return (u16)((u + 0x7fffu + ((u >> 16) & 1u)) >> 16);
}

// ---------- fused prep: cast x -> bf16 | cast 4 weights | build Wcat ----------
__global__ __launch_bounds__(256) void prep_cast(const float* __restrict__ x, const float* __restrict__ wpr,
                                                 const float* __restrict__ w0, const float* __restrict__ w1,
                                                 const float* __restrict__ w2, const float* __restrict__ qp,
                                                 const float* __restrict__ kp, const float* __restrict__ wv,
                                                 u16* __restrict__ XB, u16* __restrict__ WPRb,
                                                 u16* __restrict__ W0b, u16* __restrict__ W1b,
                                                 u16* __restrict__ W2b, u16* __restrict__ wcat) {
  int bi = blockIdx.x, tid = threadIdx.x;
  if (bi < 2048) {                       // cast_x: 524288 float4s
    int i = bi * 256 + tid;
    float4 v = ((const float4*)x)[i];
    ushort4 o; o.x = f2b(v.x); o.y = f2b(v.y); o.z = f2b(v.z); o.w = f2b(v.w);
    ((ushort4*)XB)[i] = o;
  } else if (bi < 3072) {                // cast 4x 512x512 weights: 262144 float4s
    int i = (bi - 2048) * 256 + tid;
    int sel = i >> 16, j = i & 65535;
    const float* s = sel == 0 ? wpr : sel == 1 ? w0 : sel == 2 ? w1 : w2;
    u16* d = sel == 0 ? WPRb : sel == 1 ? W0b : sel == 2 ? W1b : W2b;
    float4 v = ((const float4*)s)[j];
    ushort4 o; o.x = f2b(v.x); o.y = f2b(v.y); o.z = f2b(v.z); o.w = f2b(v.w);
    ((ushort4*)d)[j] = o;
  } else {                               // build_wcat: 524288 elements
    int i = (bi - 3072) * 256 + tid;
    int d = i & 511, c = i >> 9;
    float v;
    if (c < 512) {
      int hh = c >> 5, o = c & 31;
      const float* src = (hh < 8) ? qp : kp;
      int h = hh & 7;
      v = src[(h * 512 + d) * 32 + o];
    } else {
      v = wv[(c - 512) * 512 + d];
    }
    wcat[i] = f2b(v);
  }
}

// ---------- bf16 MFMA GEMM v2: BK=64, register double-buffer prefetch ----------
// C[M x N] = A[M x 512] @ B^T.  EPI: 0 plain, 1 +X, 2 X + silu(acc). DUAL: also store bf16.
template <int EPI, bool DUAL>
__global__ __launch_bounds__(256) void mgemm(const u16* __restrict__ A, const u16* __restrict__ Bw,
                                             const float* __restrict__ X, float* __restrict__ C,
                                             u16* __restrict__ Cb, int N) {
  __shared__ u16 As[64][72];  // stride 144B = 9*16 (b128-aligned), banks 2-way max
  __shared__ u16 Bs[64][72];
  const int tid = threadIdx.x;
  const int bm = blockIdx.y, bn = blockIdx.x;
  const int lane = tid & 63, wave = tid >> 6;
  const int wm = wave >> 1, wn = wave & 1;
  const int quad = lane >> 4, l16 = lane & 15;
  const int sr = tid >> 2;        // staging row 0..63
  const int sk = (tid & 3) << 4;  // k-chunk 0,16,32,48
  floatx4 acc[2][2] = {};
  const u16* Ap = A + (size_t)(bm * 64 + sr) * 512 + sk;
  const u16* Bp = Bw + (size_t)(bn * 64 + sr) * 512 + sk;
  uint4 a0 = *(const uint4*)(Ap);
  uint4 a1 = *(const uint4*)(Ap + 8);
  uint4 b0 = *(const uint4*)(Bp);
  uint4 b1 = *(const uint4*)(Bp + 8);
  for (int k0 = 0; k0 < 512; k0 += 64) {
    __syncthreads();
    *(uint4*)&As[sr][sk] = a0;
    *(uint4*)&As[sr][sk + 8] = a1;
    *(uint4*)&Bs[sr][sk] = b0;
    *(uint4*)&Bs[sr][sk + 8] = b1;
    __syncthreads();
    if (k0 + 64 < 512) {  // prefetch next tile; latency overlaps MFMAs below
      a0 = *(const uint4*)(Ap + k0 + 64);
      a1 = *(const uint4*)(Ap + k0 + 72);
      b0 = *(const uint4*)(Bp + k0 + 64);
      b1 = *(const uint4*)(Bp + k0 + 72);
    }
#pragma unroll
    for (int kk = 0; kk < 2; kk++) {
      short8 af0 = *(const short8*)&As[wm * 32 + l16][kk * 32 + quad * 8];
      short8 af1 = *(const short8*)&As[wm * 32 + 16 + l16][kk * 32 + quad * 8];
      short8 bf0 = *(const short8*)&Bs[wn * 32 + l16][kk * 32 + quad * 8];
      short8 bf1 = *(const short8*)&Bs[wn * 32 + 16 + l16][kk * 32 + quad * 8];
      acc[0][0] = __builtin_amdgcn_mfma_f32_16x16x32_bf16(af0, bf0, acc[0][0], 0, 0, 0);
      acc[0][1] = __builtin_amdgcn_mfma_f32_16x16x32_bf16(af0, bf1, acc[0][1], 0, 0, 0);
      acc[1][0] = __builtin_amdgcn_mfma_f32_16x16x32_bf16(af1, bf0, acc[1][0], 0, 0, 0);
      acc[1][1] = __builtin_amdgcn_mfma_f32_16x16x32_bf16(af1, bf1, acc[1][1], 0, 0, 0);
    }
  }
#pragma unroll
  for (int mt = 0; mt < 2; mt++)
#pragma unroll
    for (int r = 0; r < 4; r++) {
      int row = bm * 64 + wm * 32 + mt * 16 + quad * 4 + r;
#pragma unroll
      for (int nt = 0; nt < 2; nt++) {
        int col = bn * 64 + wn * 32 + nt * 16 + l16;
        float v = acc[mt][nt][r];
        if (EPI == 1) {
          v += X[(size_t)row * 512 + col];
        } else if (EPI == 2) {
          float xv = X[(size_t)row * 512 + col];
          v = xv + v / (1.f + __expf(-v));
        }
        C[(size_t)row * N + col] = v;
        if (DUAL) Cb[(size_t)row * N + col] = f2b(v);
      }
    }
}

// ---------- fused prep_attn: RoPE q,k -> bf16 (b,h,t,32) | V -> bf16 (b,h,64,T) ----------
__global__ __launch_bounds__(256) void prep_attn(const float* __restrict__ qkv, const float* __restrict__ qgain,
                                                 u16* __restrict__ qr, u16* __restrict__ kr,
                                                 u16* __restrict__ Vt) {
  const int bi = blockIdx.x, tid = threadIdx.x;
  if (bi < 2048) {  // RoPE
    int gid = bi * 256 + tid;
    int o = gid & 15;
    int t = (gid >> 4) & 2047;
    int h = (gid >> 15) & 7;
    int b = gid >> 18;
    const float* row = qkv + (size_t)(b * 2048 + t) * 1024;
    float freq = powf(10000.f, -(float)o / 16.f);
    float ang = (float)t * freq;
    float s, c;
    sincosf(ang, &s, &c);
    float g = qgain[h] * 0.17677669529663687f;  // gain * 1/sqrt(32)
    int qb = h * 32;
    float q0 = row[qb + o], q1 = row[qb + o + 16];
    float k0 = row[256 + qb + o], k1 = row[256 + qb + o + 16];
    u16* qo = qr + ((size_t)((b * 8 + h) * 2048 + t)) * 32;
    u16* ko = kr + ((size_t)((b * 8 + h) * 2048 + t)) * 32;
    qo[o] = f2b((q0 * c - q1 * s) * g);
    qo[o + 16] = f2b((q1 * c + q0 * s) * g);
    ko[o] = f2b(k0 * c - k1 * s);
    ko[o + 16] = f2b(k1 * c + k0 * s);
  } else {  // V transpose
    int idx = bi - 2048;
    const int tt = idx & 31, bh = idx >> 5;
    const int b = bh >> 3, h = bh & 7;
    __shared__ u16 Ts[64][72];
    const int r = tid >> 2, q = tid & 3;
    const float* src = qkv + ((size_t)(b * 2048 + tt * 64 + r)) * 1024 + 512 + h * 64 + q * 16;
#pragma unroll
    for (int j = 0; j < 4; j++) {
      float4 v = *(const float4*)(src + j * 4);
      Ts[q * 16 + j * 4 + 0][r] = f2b(v.x);
      Ts[q * 16 + j * 4 + 1][r] = f2b(v.y);
      Ts[q * 16 + j * 4 + 2][r] = f2b(v.z);
      Ts[q * 16 + j * 4 + 3][r] = f2b(v.w);
    }
    __syncthreads();
    u16* dst = Vt + ((size_t)(bh * 64 + r)) * 2048 + tt * 64 + q * 16;
    *(uint4*)dst = *(const uint4*)&Ts[r][q * 16];
    *(uint4*)(dst + 8) = *(const uint4*)&Ts[r][q * 16 + 8];
  }
}

// ---------- MFMA causal attention, split-K (S=2), no-max softmax, K/V prefetch ----------
__global__ __launch_bounds__(256) void attn_split(const u16* __restrict__ Qb, const u16* __restrict__ Kb,
                                                  const u16* __restrict__ Vt, float* __restrict__ PO,
                                                  float* __restrict__ PL) {
  const int bi = blockIdx.x;               // 1024 blocks
  const int bh = bi & 15;
  const int q0i = (bi >> 4) & 15;
  const int rem = bi >> 8;                 // blocks j,j+256,j+512,j+768 share a CU:
  const int qt = (rem & 1) ? (31 - q0i) : q0i;  // per-CU work = const 33 iters
  const int s = rem >> 1;
  const int tid = threadIdx.x;
  const int w = tid >> 6, lane = tid & 63, quad = lane >> 4, l16 = lane & 15;
  __shared__ u16 Vts[64][72];
  __shared__ u16 Ps[4][16][72];

  const int mid = (qt + 1) >> 1;
  const int kt_beg = s ? mid : 0;
  const int kt_end = s ? (qt + 1) : mid;

  short8 qfrag = *(const short8*)(Qb + ((size_t)(bh * 2048 + qt * 64 + w * 16 + l16)) * 32 + quad * 8);
  floatx4 o_acc[4] = {};
  float l_part[4] = {0.f, 0.f, 0.f, 0.f};
  const u16* Kbase = Kb + (size_t)bh * 2048 * 32;
  const u16* Vtb = Vt + (size_t)bh * 64 * 2048;
  const int vr = tid >> 2, vc = (tid & 3) << 4;

  uint4 v0 = {}, v1 = {};
  short8 kf[4] = {};
  if (kt_beg < kt_end) {
    const u16* src = Vtb + (size_t)vr * 2048 + kt_beg * 64 + vc;
    v0 = *(const uint4*)src;
    v1 = *(const uint4*)(src + 8);
#pragma unroll
    for (int nt = 0; nt < 4; nt++)
      kf[nt] = *(const short8*)(Kbase + (size_t)(kt_beg * 64 + nt * 16 + l16) * 32 + quad * 8);
  }

  for (int kt = kt_beg; kt < kt_end; ++kt) {
    __syncthreads();
    *(uint4*)&Vts[vr][vc] = v0;
    *(uint4*)&Vts[vr][vc + 8] = v1;
    __syncthreads();
    const bool more = (kt + 1 < kt_end);
    uint4 v0n = {}, v1n = {};
    short8 kfn[4] = {};
    if (more) {  // prefetch next K/V; latency overlaps exp+MFMA below
      const u16* src = Vtb + (size_t)vr * 2048 + (kt + 1) * 64 + vc;
      v0n = *(const uint4*)src;
      v1n = *(const uint4*)(src + 8);
#pragma unroll
      for (int nt = 0; nt < 4; nt++)
        kfn[nt] = *(const short8*)(Kbase + (size_t)((kt + 1) * 64 + nt * 16 + l16) * 32 + quad * 8);
    }

    floatx4 s_acc[4];
#pragma unroll
    for (int nt = 0; nt < 4; nt++) {
      floatx4 zz = {0.f, 0.f, 0.f, 0.f};
      s_acc[nt] = __builtin_amdgcn_mfma_f32_16x16x32_bf16(qfrag, kf[nt], zz, 0, 0, 0);
    }
    const bool diag = (kt == qt);
#pragma unroll
    for (int r = 0; r < 4; r++) {
      int mloc = w * 16 + quad * 4 + r;
      float psum = 0.f;
#pragma unroll
      for (int nt = 0; nt < 4; nt++) {
        float p = __expf(s_acc[nt][r]);  // scores O(1): no max subtraction needed
        if (diag && (nt * 16 + l16) > mloc) p = 0.f;
        psum += p;
        Ps[w][quad * 4 + r][nt * 16 + l16] = f2b(p);
      }
      l_part[r] += psum;
    }
#pragma unroll
    for (int kc = 0; kc < 2; kc++) {
      short8 pf = *(const short8*)&Ps[w][l16][kc * 32 + quad * 8];
#pragma unroll
      for (int nt = 0; nt < 4; nt++) {
        short8 vf = *(const short8*)&Vts[nt * 16 + l16][kc * 32 + quad * 8];
        o_acc[nt] = __builtin_amdgcn_mfma_f32_16x16x32_bf16(pf, vf, o_acc[nt], 0, 0, 0);
      }
    }
    v0 = v0n; v1 = v1n;
#pragma unroll
    for (int nt = 0; nt < 4; nt++) kf[nt] = kfn[nt];
  }

  // store partials (unnormalized O, per-row l)
  const int pidx = (bh * 32 + qt) * 2 + s;
  float* pob = PO + (size_t)pidx * 4096;
#pragma unroll
  for (int r = 0; r < 4; r++) {
    float ls = l_part[r];
#pragma unroll
    for (int mk = 1; mk < 16; mk <<= 1) ls += __shfl_xor(ls, mk, 64);
    int row = w * 16 + quad * 4 + r;
#pragma unroll
    for (int nt = 0; nt < 4; nt++) pob[row * 64 + nt * 16 + l16] = o_acc[nt][r];
    if (l16 == 0) PL[pidx * 64 + row] = ls;
  }
}

// ---------- combine split-K partials + self-align + permute to (b,t,512) bf16 ----------
// grid must be 8192: 32768 (bh,tok) rows, 4 per block.
__global__ __launch_bounds__(256) void attn_combine(const float* __restrict__ PO, const float* __restrict__ PL,
                                                    const float* __restrict__ qkv, u16* __restrict__ y2b) {
  int ridx = blockIdx.x * 4 + (threadIdx.x >> 6);  // 0..32767
  int lane = threadIdx.x & 63;
  int bh = ridx >> 11, tok = ridx & 2047;
  int qt = tok >> 6, row = tok & 63;
  int pidx = (bh * 32 + qt) * 2;
  const float* p0 = PO + (size_t)pidx * 4096 + row * 64;
  float o = p0[lane] + p0[4096 + lane];
  float l = PL[pidx * 64 + row] + PL[(pidx + 1) * 64 + row];
  float yv = o / l;
  int b = bh >> 3, h = bh & 7;
  float vv = qkv[(size_t)(b * 2048 + tok) * 1024 + 512 + h * 64 + lane];
  float ss = vv * vv, dot = yv * vv;
#pragma unroll
  for (int mk = 1; mk < 64; mk <<= 1) {
    ss += __shfl_xor(ss, mk, 64);
    dot += __shfl_xor(dot, mk, 64);
  }
  float coef = dot / fmaxf(ss, 1e-24f);
  y2b[(size_t)(b * 2048 + tok) * 512 + h * 64 + lane] = f2b(yv - coef * vv);
}

// ---------- LayerNorm (bf16 out): one wave per 512-row ----------
__global__ __launch_bounds__(256) void ln_kernel(const float* __restrict__ in, const float* __restrict__ g,
                                                 const float* __restrict__ bglob, u16* __restrict__ outb) {
  int row = blockIdx.x * 4 + (threadIdx.x >> 6);
  int lane = threadIdx.x & 63;
  const float* rp = in + (size_t)row * 512 + lane * 8;
  float4 a = *(const float4*)rp;
  float4 b = *(const float4*)(rp + 4);
  float v[8] = {a.x, a.y, a.z, a.w, b.x, b.y, b.z, b.w};
  float s = 0.f;
#pragma unroll
  for (int e = 0; e < 8; e++) s += v[e];
#pragma unroll
  for (int mk = 1; mk < 64; mk <<= 1) s += __shfl_xor(s, mk, 64);
  float mean = s * (1.f / 512.f);
  float vs = 0.f;
#pragma unroll
  for (int e = 0; e < 8; e++) { float d = v[e] - mean; vs = fmaf(d, d, vs); }
#pragma unroll
  for (int mk = 1; mk < 64; mk <<= 1) vs += __shfl_xor(vs, mk, 64);
  float inv = rsqrtf(vs * (1.f / 512.f) + 1e-5f);
  int c0 = lane * 8;
  u16* op = outb + (size_t)row * 512 + c0;
  ushort4 o1, o2;
  o1.x = f2b((v[0] - mean) * inv * g[c0 + 0] + bglob[c0 + 0]);
  o1.y = f2b((v[1] - mean) * inv * g[c0 + 1] + bglob[c0 + 1]);
  o1.z = f2b((v[2] - mean) * inv * g[c0 + 2] + bglob[c0 + 2]);
  o1.w = f2b((v[3] - mean) * inv * g[c0 + 3] + bglob[c0 + 3]);
  o2.x = f2b((v[4] - mean) * inv * g[c0 + 4] + bglob[c0 + 4]);
  o2.y = f2b((v[5] - mean) * inv * g[c0 + 5] + bglob[c0 + 5]);
  o2.z = f2b((v[6] - mean) * inv * g[c0 + 6] + bglob[c0 + 6]);
  o2.w = f2b((v[7] - mean) * inv * g[c0 + 7] + bglob[c0 + 7]);
  *(ushort4*)op = o1;
  *(ushort4*)(op + 4) = o2;
}

// ---------- fused RMS + 512->32 projection + softplus temp + tanh ----------
__global__ __launch_bounds__(256) void final_rms(const float* __restrict__ he2, const float* __restrict__ wout,
                                                 const float* __restrict__ ct, float* __restrict__ z) {
  int tok = blockIdx.x * 8 + (threadIdx.x >> 5);
  int n = threadIdx.x & 31;
  const float* rr = he2 + (size_t)tok * 512;
  float ss = 0.f;
#pragma unroll
  for (int j = 0; j < 4; j++) {
    float4 v = ((const float4*)rr)[j * 32 + n];
    ss = fmaf(v.x, v.x, fmaf(v.y, v.y, fmaf(v.z, v.z, fmaf(v.w, v.w, ss))));
  }
#pragma unroll
  for (int mk = 1; mk < 32; mk <<= 1) ss += __shfl_xor(ss, mk, 64);
  float rinv = rsqrtf(ss * (1.f / 512.f) + 1e-6f);
  const float* w = wout + (size_t)n * 512;
  float acc = 0.f;
  for (int d = 0; d < 512; d += 4) {
    float4 rv = *(const float4*)(rr + d);
    float4 wv = *(const float4*)(w + d);
    acc = fmaf(rv.x, wv.x, acc);
    acc = fmaf(rv.y, wv.y, acc);
    acc = fmaf(rv.z, wv.z, acc);
    acc = fmaf(rv.w, wv.w, acc);
  }
  float c = ct[n];
  float sp = (c > 20.f) ? c : log1pf(__expf(c));
  z[(size_t)tok * 32 + n] = tanhf(acc * rinv / (sp + 1e-4f));
}

extern "C" void kernel_launch(void* const* d_in, const int* in_sizes, int n_in,
                              void* d_out, int out_size, void* d_ws, size_t ws_size,
                              hipStream_t stream) {
  const float* x = (const float*)d_in[0];
  const float* qp = (const float*)d_in[1];
  const float* kp = (const float*)d_in[2];
  const float* wv = (const float*)d_in[3];
  const float* wpr = (const float*)d_in[4];
  const float* qg = (const float*)d_in[5];
  const float* w0 = (const float*)d_in[6];
  const float* g1 = (const float*)d_in[7];
  const float* b1 = (const float*)d_in[8];
  const float* w1 = (const float*)d_in[9];
  const float* g2 = (const float*)d_in[10];
  const float* b2 = (const float*)d_in[11];
  const float* w2 = (const float*)d_in[12];
  const float* wout = (const float*)d_in[13];
  const float* ct = (const float*)d_in[14];
  float* z = (float*)d_out;

  float* ws = (float*)d_ws;
  const size_t MEG = 1024 * 1024;
  float* A_QKV = ws;                          // [0..4M) fp32 qkv; later he0
  u16* A_Qb = (u16*)(ws + 4 * MEG);           // [4M..4.5M)
  u16* A_Kb = (u16*)(ws + 4 * MEG + 524288);  // [4.5M..5M)
  u16* A_Vt = (u16*)(ws + 5 * MEG);           // [5M..6M)
  float* A_HE2 = ws + 4 * MEG;                // alias (after attention)
  float* A_PO = ws + 6 * MEG;                 // [6M..10M): split-K partial O (4M floats)
  float* A_Y = ws + 6 * MEG;                  // later: he1 fp32 [6M..8M)
  float* A_H = ws + 8 * MEG;                  // later: h fp32 [8M..10M)
  u16* A_Y2b = (u16*)(ws + 10 * MEG);         // [10M..11M)
  u16* A_Hb = (u16*)(ws + 11 * MEG);          // [11M..12M)
  u16* A_LNb = (u16*)(ws + 12 * MEG);         // [12M..13M)
  u16* XB = (u16*)(ws + 13 * MEG);            // [13M..14M); reused as PL after QKV gemm
  float* A_PL = ws + 13 * MEG;                // 64K floats (aliases dead XB)
  u16* WCATb = (u16*)(ws + 14 * MEG);         // [14M..14.25M)
  u16* WPRb = WCATb + 524288;
  u16* W0b = WPRb + 262144;
  u16* W1b = W0b + 262144;
  u16* W2b = W1b + 262144;

  hipLaunchKernelGGL(prep_cast, dim3(5120), dim3(256), 0, stream, x, wpr, w0, w1, w2, qp, kp, wv,
                     XB, WPRb, W0b, W1b, W2b, WCATb);
  hipLaunchKernelGGL((mgemm<0, false>), dim3(16, 64), dim3(256), 0, stream, XB, WCATb,
                     (const float*)nullptr, A_QKV, (u16*)nullptr, 1024);
  hipLaunchKernelGGL(prep_attn, dim3(2560), dim3(256), 0, stream, A_QKV, qg, A_Qb, A_Kb, A_Vt);
  hipLaunchKernelGGL(attn_split, dim3(1024), dim3(256), 0, stream, A_Qb, A_Kb, A_Vt, A_PO, A_PL);
  hipLaunchKernelGGL(attn_combine, dim3(8192), dim3(256), 0, stream, A_PO, A_PL, A_QKV, A_Y2b);
  // h = y2 @ wpr^T + x   (dual store fp32+bf16)
  hipLaunchKernelGGL((mgemm<1, true>), dim3(8, 64), dim3(256), 0, stream, A_Y2b, WPRb, x, A_H, A_Hb, 512);
  // he0 = h @ w0^T
  hipLaunchKernelGGL((mgemm<0, false>), dim3(8, 64), dim3(256), 0, stream, A_Hb, W0b,
                     (const float*)nullptr, A_QKV, (u16*)nullptr, 512);
  hipLaunchKernelGGL(ln_kernel, dim3(1024), dim3(256), 0, stream, A_QKV, g1, b1, A_LNb);
  // he1 = h + silu(ln1 @ w1^T)
  hipLaunchKernelGGL((mgemm<2, false>), dim3(8, 64), dim3(256), 0, stream, A_LNb, W1b, A_H, A_Y,
                     (u16*)nullptr, 512);
  hipLaunchKernelGGL(ln_kernel, dim3(1024), dim3(256), 0, stream, A_Y, g2, b2, A_LNb);
  // he2 = he1 + silu(ln2 @ w2^T)
  hipLaunchKernelGGL((mgemm<2, false>), dim3(8, 64), dim3(256), 0, stream, A_LNb, W2b, A_Y, A_HE2,
                     (u16*)nullptr, 512);
  hipLaunchKernelGGL(final_rms, dim3(512), dim3(256), 0, stream, A_HE2, wout, ct, z);
}